// Round 15
// baseline (404.410 us; speedup 1.0000x reference)
//
#include <hip/hip_runtime.h>
#include <hip/hip_fp16.h>
#include <math.h>

// GAT node classification: 2 GATConv layers + ELU + log_softmax.
// N=100000, E=1600000 (+N self loops), IN=128, HEADS=4, HID=32, OUT=40.
//
// Rules learned:
//  - R4: every __shfl executes with ALL 64 lanes active; wave-uniform bounds;
//    predicate VALUES not control flow.
//  - R8: __shfl returns the SOURCE lane's evaluation of its operand; do
//    consumer-side selection AFTER the shfl.
//  - R9: same-address global atomics from 25K blocks serialize. Global max
//    reduction uses a dedicated 256-block kernel.
//  - R10: diff-check unrolled FMA blocks line-by-line after mechanical edits.
//  - R12: 2-deep gather unroll is the sweet spot.
//  - R14: feature accumulation in packed fp16 (__hfma2); logits/dens f32.
//  - R15: al1/al2 fused into the GEMMs (acc already in registers; 32-lane
//    shfl reduce / LDS atomic per-row reduce) -- kills 2 dispatches + re-reads.

#define SLOPE 0.2f
#define NB 512
#define NBSHIFT 9

#if defined(__has_builtin)
#if __has_builtin(__builtin_amdgcn_fdot2)
#define HAS_FDOT2 1
#endif
#endif

typedef _Float16 h2v __attribute__((ext_vector_type(2)));

__device__ __forceinline__ float dot2f(__half2 a, __half2 b, float c) {
#ifdef HAS_FDOT2
    return __builtin_amdgcn_fdot2(*reinterpret_cast<h2v*>(&a),
                                  *reinterpret_cast<h2v*>(&b), c, false);
#else
    float2 af = __half22float2(a), bf = __half22float2(b);
    return fmaf(af.y, bf.y, fmaf(af.x, bf.x, c));
#endif
}

__device__ __forceinline__ unsigned fenc(float f) {
    unsigned b = __float_as_uint(f);
    return (b & 0x80000000u) ? ~b : (b | 0x80000000u);
}
__device__ __forceinline__ float fdec(unsigned u) {
    return __uint_as_float((u & 0x80000000u) ? (u ^ 0x80000000u) : ~u);
}
__device__ __forceinline__ __half2 i2h2(int i) { return *reinterpret_cast<__half2*>(&i); }
__device__ __forceinline__ int h22i(__half2 h) { return *reinterpret_cast<int*>(&h); }
__device__ __forceinline__ __half2 h2shflxor(__half2 v, int off) {
    int j = __shfl_xor(h22i(v), off);
    return i2h2(j);
}

// ---------------- CSR construction (bucket sort) ----------------

__global__ __launch_bounds__(256) void k_init(unsigned* gcnt, unsigned* gmaxu, int nbuck) {
    int i = blockIdx.x * 256 + threadIdx.x;
    if (i < nbuck) gcnt[i] = 0u;
    if (i < 8) gmaxu[i] = 0u;   // enc(-huge)
}

__global__ __launch_bounds__(256) void k_bin(const int* __restrict__ src, const int* __restrict__ dst,
                                             unsigned* __restrict__ gcnt, unsigned* __restrict__ binbuf,
                                             int E, int nbuck, int cap, int epb) {
    __shared__ unsigned hist[256];
    __shared__ unsigned base[256];
    __shared__ unsigned cur[256];
    int t = threadIdx.x;
    if (t < nbuck) { hist[t] = 0u; cur[t] = 0u; }
    __syncthreads();
    int e0 = blockIdx.x * epb;
    int e1 = min(E, e0 + epb);
    for (int e = e0 + t; e < e1; e += 256) {
        int bk = dst[e] >> NBSHIFT;
        atomicAdd(&hist[bk], 1u);
    }
    __syncthreads();
    if (t < nbuck) base[t] = hist[t] ? atomicAdd(&gcnt[t], hist[t]) : 0u;
    __syncthreads();
    for (int e = e0 + t; e < e1; e += 256) {
        int d = dst[e];
        int bk = d >> NBSHIFT;
        unsigned p = atomicAdd(&cur[bk], 1u);
        binbuf[(size_t)bk * cap + base[bk] + p] =
            ((unsigned)src[e] << NBSHIFT) | (unsigned)(d & (NB - 1));
    }
}

__global__ __launch_bounds__(256) void k_bscan(const unsigned* __restrict__ gcnt, unsigned* __restrict__ gbase,
                                               int* __restrict__ row, int n, int nbuck, int etot) {
    __shared__ unsigned s[256];
    int t = threadIdx.x;
    unsigned v = 0u;
    if (t < nbuck) {
        int nodes = min(NB, n - t * NB);
        v = gcnt[t] + (unsigned)nodes;
    }
    s[t] = v;
    __syncthreads();
    for (int off = 1; off < 256; off <<= 1) {
        unsigned x = (t >= off) ? s[t - off] : 0u;
        __syncthreads();
        s[t] += x;
        __syncthreads();
    }
    if (t < nbuck) gbase[t] = s[t] - v;  // exclusive
    if (t == 0) row[n] = etot;
}

__global__ __launch_bounds__(256) void k_build(const unsigned* __restrict__ gcnt, const unsigned* __restrict__ gbase,
                                               const unsigned* __restrict__ binbuf, int* __restrict__ row,
                                               int* __restrict__ csr, int n, int cap) {
    __shared__ int s_cnt[NB];
    __shared__ int s_off[NB];
    __shared__ int sums[256];
    int b = blockIdx.x;
    int t = threadIdx.x;
    int nn = min(NB, n - b * NB);
    int total = (int)gcnt[b];
    int base = (int)gbase[b];
    s_cnt[t] = 0; s_cnt[t + 256] = 0;
    __syncthreads();
    const unsigned* rec = binbuf + (size_t)b * cap;
    for (int r = t; r < total; r += 256) atomicAdd(&s_cnt[rec[r] & (NB - 1)], 1);
    __syncthreads();
    int i0 = 2 * t, i1 = 2 * t + 1;
    int v0 = (i0 < nn) ? s_cnt[i0] + 1 : 0;
    int v1 = (i1 < nn) ? s_cnt[i1] + 1 : 0;
    int ps = v0 + v1;
    sums[t] = ps;
    __syncthreads();
    for (int off = 1; off < 256; off <<= 1) {
        int x = (t >= off) ? sums[t - off] : 0;
        __syncthreads();
        sums[t] += x;
        __syncthreads();
    }
    int ex = sums[t] - ps;
    s_off[i0] = ex;
    s_off[i1] = ex + v0;
    if (i0 < nn) { row[b * NB + i0] = base + ex;      csr[base + ex]      = b * NB + i0; }
    if (i1 < nn) { row[b * NB + i1] = base + ex + v0; csr[base + ex + v0] = b * NB + i1; }
    __syncthreads();
    s_cnt[t] = 1; s_cnt[t + 256] = 1;   // cursor: slot 0 = self loop
    __syncthreads();
    for (int r = t; r < total; r += 256) {
        unsigned rc = rec[r];
        int ld = rc & (NB - 1);
        int p = atomicAdd(&s_cnt[ld], 1);
        csr[base + s_off[ld] + p] = (int)(rc >> NBSHIFT);
    }
}

// ------- Layer 1 GEMM + fused al1: h1 = x @ W1, als/ald dots from f32 acc -------

__global__ __launch_bounds__(256) void k_gemm1(const float* __restrict__ x, const float* __restrict__ W,
                                               const float* __restrict__ asrc, const float* __restrict__ adst,
                                               __half* __restrict__ hh, float* __restrict__ als,
                                               float* __restrict__ ald, int n) {
    __shared__ __half2 xs2[32][64];     // [row][k2]
    __shared__ __half  wst[128][34];    // [c][kk] transposed W chunk; +2 pad
    int t = threadIdx.x;
    int row0 = blockIdx.x * 32;
#pragma unroll
    for (int i = 0; i < 4; i++) {
        int flat = t + 256 * i;
        int r = flat >> 5, c4 = flat & 31;
        int gr = row0 + r;
        float4 v = make_float4(0.f, 0.f, 0.f, 0.f);
        if (gr < n) v = ((const float4*)(x + (size_t)gr * 128))[c4];
        xs2[r][c4 * 2]     = __floats2half2_rn(v.x, v.y);
        xs2[r][c4 * 2 + 1] = __floats2half2_rn(v.z, v.w);
    }
    int ty = t >> 5;
    int tx = t & 31;
    float acc[4][4] = {};
    for (int kc = 0; kc < 4; ++kc) {
        __syncthreads();
#pragma unroll
        for (int i = 0; i < 4; i++) {
            int flat = t + 256 * i;
            int kk = flat >> 5, c4 = flat & 31;
            float4 v = ((const float4*)(W + (size_t)(kc * 32 + kk) * 128))[c4];
            wst[c4 * 4 + 0][kk] = __float2half_rn(v.x);
            wst[c4 * 4 + 1][kk] = __float2half_rn(v.y);
            wst[c4 * 4 + 2][kk] = __float2half_rn(v.z);
            wst[c4 * 4 + 3][kk] = __float2half_rn(v.w);
        }
        __syncthreads();
#pragma unroll
        for (int kk2 = 0; kk2 < 16; ++kk2) {
            __half2 wv[4];
#pragma unroll
            for (int j = 0; j < 4; j++)
                wv[j] = *(const __half2*)&wst[tx + 32 * j][kk2 * 2];
#pragma unroll
            for (int r = 0; r < 4; r++) {
                __half2 xv = xs2[ty + 8 * r][kc * 16 + kk2];
#pragma unroll
                for (int j = 0; j < 4; j++)
                    acc[r][j] = dot2f(xv, wv[j], acc[r][j]);
            }
        }
    }
    // per-head attention vectors: head j owns channel tx+32j -> a[j*32+tx]
    float vs0 = asrc[tx], vs1 = asrc[32 + tx], vs2 = asrc[64 + tx], vs3 = asrc[96 + tx];
    float vd0 = adst[tx], vd1 = adst[32 + tx], vd2 = adst[64 + tx], vd3 = adst[96 + tx];
#pragma unroll
    for (int r = 0; r < 4; r++) {
        int gr = row0 + ty + 8 * r;
        if (gr < n) {
#pragma unroll
            for (int j = 0; j < 4; j++)
                hh[(size_t)gr * 128 + tx + 32 * j] = __float2half_rn(acc[r][j]);
        }
        // fused al1: reduce over the 32-lane tx group (offsets 1..16 stay
        // inside the group; all 64 lanes execute -- R4).
        float ps0 = acc[r][0] * vs0, ps1 = acc[r][1] * vs1;
        float ps2 = acc[r][2] * vs2, ps3 = acc[r][3] * vs3;
        float pd0 = acc[r][0] * vd0, pd1 = acc[r][1] * vd1;
        float pd2 = acc[r][2] * vd2, pd3 = acc[r][3] * vd3;
#pragma unroll
        for (int off = 1; off <= 16; off <<= 1) {
            ps0 += __shfl_xor(ps0, off); ps1 += __shfl_xor(ps1, off);
            ps2 += __shfl_xor(ps2, off); ps3 += __shfl_xor(ps3, off);
            pd0 += __shfl_xor(pd0, off); pd1 += __shfl_xor(pd1, off);
            pd2 += __shfl_xor(pd2, off); pd3 += __shfl_xor(pd3, off);
        }
        if (tx == 0 && gr < n) {
            float4 s4 = make_float4(ps0, ps1, ps2, ps3);
            float4 d4 = make_float4(pd0, pd1, pd2, pd3);
            *(float4*)(als + (size_t)gr * 4) = s4;
            *(float4*)(ald + (size_t)gr * 4) = d4;
        }
    }
}

// global per-head max of als (256 blocks -> ~1K same-address atomics, OK)
__global__ __launch_bounds__(256) void k_gmax4(const float4* __restrict__ als4, unsigned* gm, int n) {
    float m0 = -INFINITY, m1 = -INFINITY, m2 = -INFINITY, m3 = -INFINITY;
    for (int i = blockIdx.x * 256 + threadIdx.x; i < n; i += 256 * 256) {
        float4 v = als4[i];
        m0 = fmaxf(m0, v.x); m1 = fmaxf(m1, v.y);
        m2 = fmaxf(m2, v.z); m3 = fmaxf(m3, v.w);
    }
#pragma unroll
    for (int off = 32; off; off >>= 1) {
        m0 = fmaxf(m0, __shfl_xor(m0, off));
        m1 = fmaxf(m1, __shfl_xor(m1, off));
        m2 = fmaxf(m2, __shfl_xor(m2, off));
        m3 = fmaxf(m3, __shfl_xor(m3, off));
    }
    __shared__ float sm[4][4];
    int wid = threadIdx.x >> 6;
    if ((threadIdx.x & 63) == 0) { sm[wid][0] = m0; sm[wid][1] = m1; sm[wid][2] = m2; sm[wid][3] = m3; }
    __syncthreads();
    if (threadIdx.x == 0) {
        float r0 = sm[0][0], r1 = sm[0][1], r2 = sm[0][2], r3 = sm[0][3];
        for (int w = 1; w < 4; w++) {
            r0 = fmaxf(r0, sm[w][0]); r1 = fmaxf(r1, sm[w][1]);
            r2 = fmaxf(r2, sm[w][2]); r3 = fmaxf(r3, sm[w][3]);
        }
        atomicMax(gm + 0, fenc(r0)); atomicMax(gm + 1, fenc(r1));
        atomicMax(gm + 2, fenc(r2)); atomicMax(gm + 3, fenc(r3));
    }
}

__global__ __launch_bounds__(256) void k_gmax1(const float* __restrict__ als, unsigned* gm, int n) {
    float m = -INFINITY;
    for (int i = blockIdx.x * 256 + threadIdx.x; i < n; i += 256 * 256) m = fmaxf(m, als[i]);
#pragma unroll
    for (int off = 32; off; off >>= 1) m = fmaxf(m, __shfl_xor(m, off));
    __shared__ float sm[4];
    int wid = threadIdx.x >> 6;
    if ((threadIdx.x & 63) == 0) sm[wid] = m;
    __syncthreads();
    if (threadIdx.x == 0)
        atomicMax(gm, fenc(fmaxf(fmaxf(sm[0], sm[1]), fmaxf(sm[2], sm[3]))));
}

// wave per dst node, single edge pass, prep-then-broadcast (2-deep, R12),
// packed fp16 accumulation (R14).
// Groups: g=lane>>4, lig=lane&15 (8 ch each), head=lig>>2.
__global__ __launch_bounds__(256) void k_agg1(const int* __restrict__ row, const int* __restrict__ csr,
                                              const float* __restrict__ als, const float* __restrict__ ald,
                                              const __half* __restrict__ h, const float* __restrict__ b,
                                              const unsigned* __restrict__ gmaxu, __half* __restrict__ out,
                                              int n) {
    int node = blockIdx.x * 4 + (threadIdx.x >> 6);
    if (node >= n) return;
    int lane = threadIdx.x & 63;
    int start = __builtin_amdgcn_readfirstlane(row[node]);
    int end   = __builtin_amdgcn_readfirstlane(row[node + 1]);

    int g = lane >> 4;
    int lig = lane & 15;
    int head = lig >> 2;

    float4 adv = *(const float4*)(ald + (size_t)node * 4);
    uint4 gu = *(const uint4*)gmaxu;
    float mt, mh0, mh1, mh2, mh3;
    mt = fdec(gu.x) + adv.x; mh0 = mt > 0.f ? mt : SLOPE * mt;
    mt = fdec(gu.y) + adv.y; mh1 = mt > 0.f ? mt : SLOPE * mt;
    mt = fdec(gu.z) + adv.z; mh2 = mt > 0.f ? mt : SLOPE * mt;
    mt = fdec(gu.w) + adv.w; mh3 = mt > 0.f ? mt : SLOPE * mt;

    const __half2 z2 = __floats2half2_rn(0.f, 0.f);
    float den0 = 0.f, den1 = 0.f, den2 = 0.f, den3 = 0.f;
    __half2 ah0 = z2, ah1 = z2, ah2 = z2, ah3 = z2;   // 8 fp16 channel accumulators

    for (int k0 = start; k0 < end; k0 += 64) {
        int nb = end - k0; if (nb > 64) nb = 64;
        // ---- prep: this lane's edge -> 4 exps, pack to 2x half2 ----
        int s_l = (lane < nb) ? csr[k0 + lane] : 0;
        float4 av = *(const float4*)(als + (size_t)s_l * 4);
        float e, x0, x1, x2, x3;
        e = av.x + adv.x; e = e > 0.f ? e : SLOPE * e; x0 = __expf(e - mh0);
        e = av.y + adv.y; e = e > 0.f ? e : SLOPE * e; x1 = __expf(e - mh1);
        e = av.z + adv.z; e = e > 0.f ? e : SLOPE * e; x2 = __expf(e - mh2);
        e = av.w + adv.w; e = e > 0.f ? e : SLOPE * e; x3 = __expf(e - mh3);
        bool valid = lane < nb;
        x0 = valid ? x0 : 0.f; x1 = valid ? x1 : 0.f;
        x2 = valid ? x2 : 0.f; x3 = valid ? x3 : 0.f;
        den0 += x0; den1 += x1; den2 += x2; den3 += x3;
        __half2 p01 = __floats2half2_rn(x0, x1);
        __half2 p23 = __floats2half2_rn(x2, x3);
        int w01 = h22i(p01);
        int w23 = h22i(p23);

        // ---- gather: 8 edges per unrolled iter (4 groups x 2) ----
        for (int jj = 0; jj < nb; jj += 8) {
            int eA = jj + g;        // <= 63
            int eB = jj + 4 + g;    // <= 63
            int sA = __shfl(s_l, eA);
            int sB = __shfl(s_l, eB);
            // R8 rule: shfl RAW words; select by THIS lane's head afterwards.
            int wA01 = __shfl(w01, eA);
            int wA23 = __shfl(w23, eA);
            int wB01 = __shfl(w01, eB);
            int wB23 = __shfl(w23, eB);
            int wA = (head & 2) ? wA23 : wA01;
            int wB = (head & 2) ? wB23 : wB01;
            uint4 hvA = *(const uint4*)(h + ((size_t)sA << 7) + lig * 8);
            uint4 hvB = *(const uint4*)(h + ((size_t)sB << 7) + lig * 8);
            __half exhA = (head & 1) ? __high2half(i2h2(wA)) : __low2half(i2h2(wA));
            __half exhB = (head & 1) ? __high2half(i2h2(wB)) : __low2half(i2h2(wB));
            __half2 exA2 = __half2half2(exhA);
            __half2 exB2 = __half2half2(exhB);
            exA2 = (eA < nb) ? exA2 : z2;   // value-predicate (R4)
            exB2 = (eB < nb) ? exB2 : z2;
            ah0 = __hfma2(exA2, i2h2((int)hvA.x), ah0);
            ah1 = __hfma2(exA2, i2h2((int)hvA.y), ah1);
            ah2 = __hfma2(exA2, i2h2((int)hvA.z), ah2);
            ah3 = __hfma2(exA2, i2h2((int)hvA.w), ah3);
            ah0 = __hfma2(exB2, i2h2((int)hvB.x), ah0);
            ah1 = __hfma2(exB2, i2h2((int)hvB.y), ah1);
            ah2 = __hfma2(exB2, i2h2((int)hvB.z), ah2);
            ah3 = __hfma2(exB2, i2h2((int)hvB.w), ah3);
        }
    }
    // den: full 64-lane xor reduce (per-lane partials)
#pragma unroll
    for (int off = 32; off; off >>= 1) {
        den0 += __shfl_xor(den0, off);
        den1 += __shfl_xor(den1, off);
        den2 += __shfl_xor(den2, off);
        den3 += __shfl_xor(den3, off);
    }
    // accs: combine 4 groups (xor 16, 32) in packed fp16
    ah0 = __hadd2(ah0, h2shflxor(ah0, 16));
    ah1 = __hadd2(ah1, h2shflxor(ah1, 16));
    ah2 = __hadd2(ah2, h2shflxor(ah2, 16));
    ah3 = __hadd2(ah3, h2shflxor(ah3, 16));
    ah0 = __hadd2(ah0, h2shflxor(ah0, 32));
    ah1 = __hadd2(ah1, h2shflxor(ah1, 32));
    ah2 = __hadd2(ah2, h2shflxor(ah2, 32));
    ah3 = __hadd2(ah3, h2shflxor(ah3, 32));
    if (g == 0) {
        float den_h = (head & 2) ? ((head & 1) ? den3 : den2) : ((head & 1) ? den1 : den0);
        float inv = 1.f / den_h;
        float2 f0 = __half22float2(ah0);
        float2 f1 = __half22float2(ah1);
        float2 f2 = __half22float2(ah2);
        float2 f3 = __half22float2(ah3);
        float4 bv0 = *(const float4*)(b + lig * 8);
        float4 bv1 = *(const float4*)(b + lig * 8 + 4);
        float o0, o1, o2, o3, o4, o5, o6, o7;
        o0 = f0.x * inv + bv0.x; o0 = o0 > 0.f ? o0 : expm1f(o0);
        o1 = f0.y * inv + bv0.y; o1 = o1 > 0.f ? o1 : expm1f(o1);
        o2 = f1.x * inv + bv0.z; o2 = o2 > 0.f ? o2 : expm1f(o2);
        o3 = f1.y * inv + bv0.w; o3 = o3 > 0.f ? o3 : expm1f(o3);
        o4 = f2.x * inv + bv1.x; o4 = o4 > 0.f ? o4 : expm1f(o4);
        o5 = f2.y * inv + bv1.y; o5 = o5 > 0.f ? o5 : expm1f(o5);
        o6 = f3.x * inv + bv1.z; o6 = o6 > 0.f ? o6 : expm1f(o6);
        o7 = f3.y * inv + bv1.w; o7 = o7 > 0.f ? o7 : expm1f(o7);
        __half2 q0 = __floats2half2_rn(o0, o1);
        __half2 q1 = __floats2half2_rn(o2, o3);
        __half2 q2 = __floats2half2_rn(o4, o5);
        __half2 q3 = __floats2half2_rn(o6, o7);
        uint4 st;
        st.x = (unsigned)h22i(q0);
        st.y = (unsigned)h22i(q1);
        st.z = (unsigned)h22i(q2);
        st.w = (unsigned)h22i(q3);
        *(uint4*)(out + ((size_t)node << 7) + lig * 8) = st;
    }
}

// ------- Layer 2 GEMM + fused al2: h2 = hm @ W2, als/ald via LDS atomics -------

__global__ __launch_bounds__(640) void k_gemm2(const __half* __restrict__ hm, const float* __restrict__ W2,
                                               const float* __restrict__ a_s, const float* __restrict__ a_d,
                                               __half* __restrict__ h2h, float* __restrict__ als,
                                               float* __restrict__ ald, int n) {
    __shared__ float xs[16][128];
    __shared__ float ws[128 * 40];
    __shared__ float sals[16];
    __shared__ float sald[16];
    int t = threadIdx.x;
    int row0 = blockIdx.x * 16;
    if (t < 16) { sals[t] = 0.f; sald[t] = 0.f; }
    for (int i = t; i < 128 * 40; i += 640) ws[i] = W2[i];
    if (t < 256) {
        int r = t >> 4, c8 = t & 15;
        int gr = row0 + r;
        float* d = &xs[r][c8 * 8];
        if (gr < n) {
            uint4 v = *(const uint4*)(hm + (size_t)gr * 128 + c8 * 8);
            float2 f0 = __half22float2(*reinterpret_cast<__half2*>(&v.x));
            float2 f1 = __half22float2(*reinterpret_cast<__half2*>(&v.y));
            float2 f2 = __half22float2(*reinterpret_cast<__half2*>(&v.z));
            float2 f3 = __half22float2(*reinterpret_cast<__half2*>(&v.w));
            d[0] = f0.x; d[1] = f0.y; d[2] = f1.x; d[3] = f1.y;
            d[4] = f2.x; d[5] = f2.y; d[6] = f3.x; d[7] = f3.y;
        } else {
            for (int j = 0; j < 8; j++) d[j] = 0.f;
        }
    }
    __syncthreads();
    int r = t / 40, c = t - r * 40;
    int gr = row0 + r;
    float acc = 0.f;
#pragma unroll 8
    for (int k = 0; k < 128; ++k) acc += xs[r][k] * ws[k * 40 + c];
    if (gr < n) {
        h2h[(size_t)gr * 40 + c] = __float2half_rn(acc);
        atomicAdd(&sals[r], acc * a_s[c]);
        atomicAdd(&sald[r], acc * a_d[c]);
    }
    __syncthreads();
    if (t < 16 && row0 + t < n) {
        als[row0 + t] = sals[t];
        ald[row0 + t] = sald[t];
    }
}

// wave per node, single edge pass + log_softmax (2-deep, packed fp16 acc).
// Groups: g=lane/5 (12 edges in flight), lig=lane-5g (8 ch each); g==12 idle.
__global__ __launch_bounds__(256) void k_agg2(const int* __restrict__ row, const int* __restrict__ csr,
                                              const float* __restrict__ als, const float* __restrict__ ald,
                                              const __half* __restrict__ h2, const float* __restrict__ b2,
                                              const unsigned* __restrict__ gmaxu, float* __restrict__ out,
                                              int n) {
    int node = blockIdx.x * 4 + (threadIdx.x >> 6);
    if (node >= n) return;
    int lane = threadIdx.x & 63;
    int start = __builtin_amdgcn_readfirstlane(row[node]);
    int end   = __builtin_amdgcn_readfirstlane(row[node + 1]);
    float ad = ald[node];
    float mt = fdec(gmaxu[0]) + ad;
    float mh = mt > 0.f ? mt : SLOPE * mt;

    int g = lane / 5;
    int lig = lane - g * 5;
    bool act = g < 12;

    const __half2 z2 = __floats2half2_rn(0.f, 0.f);
    float den = 0.f;
    __half2 ah0 = z2, ah1 = z2, ah2 = z2, ah3 = z2;
    for (int k0 = start; k0 < end; k0 += 64) {
        int nb = end - k0; if (nb > 64) nb = 64;
        int s_l = (lane < nb) ? csr[k0 + lane] : 0;
        float e = als[s_l] + ad; e = e > 0.f ? e : SLOPE * e;
        float ex_l = __expf(e - mh);
        ex_l = (lane < nb) ? ex_l : 0.f;
        den += ex_l;
        __half exh_l = __float2half_rn(ex_l);
        int exi_l = h22i(__half2half2(exh_l));   // replicated half2

        for (int jj = 0; jj < nb; jj += 24) {
            int eA = jj + g;         // may exceed 63 -> mask + predicate
            int eB = jj + 12 + g;
            int sA = __shfl(s_l, eA & 63);
            int sB = __shfl(s_l, eB & 63);
            int exAi = __shfl(exi_l, eA & 63);
            int exBi = __shfl(exi_l, eB & 63);
            uint4 hvA = *(const uint4*)(h2 + (size_t)sA * 40 + lig * 8);
            uint4 hvB = *(const uint4*)(h2 + (size_t)sB * 40 + lig * 8);
            __half2 exA2 = i2h2(exAi);
            __half2 exB2 = i2h2(exBi);
            exA2 = (act && eA < nb) ? exA2 : z2;
            exB2 = (act && eB < nb) ? exB2 : z2;
            ah0 = __hfma2(exA2, i2h2((int)hvA.x), ah0);
            ah1 = __hfma2(exA2, i2h2((int)hvA.y), ah1);
            ah2 = __hfma2(exA2, i2h2((int)hvA.z), ah2);
            ah3 = __hfma2(exA2, i2h2((int)hvA.w), ah3);
            ah0 = __hfma2(exB2, i2h2((int)hvB.x), ah0);
            ah1 = __hfma2(exB2, i2h2((int)hvB.y), ah1);
            ah2 = __hfma2(exB2, i2h2((int)hvB.z), ah2);
            ah3 = __hfma2(exB2, i2h2((int)hvB.w), ah3);
        }
    }
    // den: full 64-lane xor reduce
#pragma unroll
    for (int off = 32; off; off >>= 1) den += __shfl_xor(den, off);
    // accs: combine 12 groups of 5 -> lanes 0-4 (packed fp16)
    int t1i;
    t1i = __shfl(h22i(ah0), (lane + 30) & 63); ah0 = __hadd2(ah0, i2h2(t1i));
    t1i = __shfl(h22i(ah1), (lane + 30) & 63); ah1 = __hadd2(ah1, i2h2(t1i));
    t1i = __shfl(h22i(ah2), (lane + 30) & 63); ah2 = __hadd2(ah2, i2h2(t1i));
    t1i = __shfl(h22i(ah3), (lane + 30) & 63); ah3 = __hadd2(ah3, i2h2(t1i));
    t1i = __shfl(h22i(ah0), (lane + 15) & 63); ah0 = __hadd2(ah0, i2h2(t1i));
    t1i = __shfl(h22i(ah1), (lane + 15) & 63); ah1 = __hadd2(ah1, i2h2(t1i));
    t1i = __shfl(h22i(ah2), (lane + 15) & 63); ah2 = __hadd2(ah2, i2h2(t1i));
    t1i = __shfl(h22i(ah3), (lane + 15) & 63); ah3 = __hadd2(ah3, i2h2(t1i));
    int t2i;
    t1i = __shfl(h22i(ah0), (lane + 5) & 63); t2i = __shfl(h22i(ah0), (lane + 10) & 63);
    ah0 = __hadd2(__hadd2(ah0, i2h2(t1i)), i2h2(t2i));
    t1i = __shfl(h22i(ah1), (lane + 5) & 63); t2i = __shfl(h22i(ah1), (lane + 10) & 63);
    ah1 = __hadd2(__hadd2(ah1, i2h2(t1i)), i2h2(t2i));
    t1i = __shfl(h22i(ah2), (lane + 5) & 63); t2i = __shfl(h22i(ah2), (lane + 10) & 63);
    ah2 = __hadd2(__hadd2(ah2, i2h2(t1i)), i2h2(t2i));
    t1i = __shfl(h22i(ah3), (lane + 5) & 63); t2i = __shfl(h22i(ah3), (lane + 10) & 63);
    ah3 = __hadd2(__hadd2(ah3, i2h2(t1i)), i2h2(t2i));

    // log_softmax epilogue: lanes 0-4 hold ch lane*8..+7
    float v0 = 0.f, v1 = 0.f, v2 = 0.f, v3 = 0.f, v4 = 0.f, v5 = 0.f, v6 = 0.f, v7 = 0.f;
    float mv = -INFINITY;
    if (lane < 5) {
        float inv = 1.f / den;
        float2 f0 = __half22float2(ah0);
        float2 f1 = __half22float2(ah1);
        float2 f2 = __half22float2(ah2);
        float2 f3 = __half22float2(ah3);
        float4 bv0 = *(const float4*)(b2 + lane * 8);
        float4 bv1 = *(const float4*)(b2 + lane * 8 + 4);
        v0 = f0.x * inv + bv0.x; v1 = f0.y * inv + bv0.y;
        v2 = f1.x * inv + bv0.z; v3 = f1.y * inv + bv0.w;
        v4 = f2.x * inv + bv1.x; v5 = f2.y * inv + bv1.y;
        v6 = f3.x * inv + bv1.z; v7 = f3.y * inv + bv1.w;
        mv = fmaxf(fmaxf(fmaxf(v0, v1), fmaxf(v2, v3)),
                   fmaxf(fmaxf(v4, v5), fmaxf(v6, v7)));
    }
#pragma unroll
    for (int off = 32; off; off >>= 1) mv = fmaxf(mv, __shfl_xor(mv, off));
    float se = 0.f;
    if (lane < 5)
        se = __expf(v0 - mv) + __expf(v1 - mv) + __expf(v2 - mv) + __expf(v3 - mv)
           + __expf(v4 - mv) + __expf(v5 - mv) + __expf(v6 - mv) + __expf(v7 - mv);
#pragma unroll
    for (int off = 32; off; off >>= 1) se += __shfl_xor(se, off);
    if (lane < 5) {
        float lse = mv + __logf(se);
        float4 o0, o1;
        o0.x = v0 - lse; o0.y = v1 - lse; o0.z = v2 - lse; o0.w = v3 - lse;
        o1.x = v4 - lse; o1.y = v5 - lse; o1.z = v6 - lse; o1.w = v7 - lse;
        *(float4*)(out + (size_t)node * 40 + lane * 8) = o0;
        *(float4*)(out + (size_t)node * 40 + lane * 8 + 4) = o1;
    }
}

// ---------------- launch ----------------

extern "C" void kernel_launch(void* const* d_in, const int* in_sizes, int n_in,
                              void* d_out, int out_size, void* d_ws, size_t ws_size,
                              hipStream_t stream) {
    const float* x   = (const float*)d_in[0];
    const int*   ei  = (const int*)d_in[1];
    const float* W1  = (const float*)d_in[2];
    const float* as1 = (const float*)d_in[3];
    const float* ad1 = (const float*)d_in[4];
    const float* b1  = (const float*)d_in[5];
    const float* W2  = (const float*)d_in[6];
    const float* as2 = (const float*)d_in[7];
    const float* ad2 = (const float*)d_in[8];
    const float* b2  = (const float*)d_in[9];
    float* out = (float*)d_out;

    int n = in_sizes[0] / 128;
    int E = in_sizes[1] / 2;
    const int* src = ei;
    const int* dst = ei + E;
    int etot = E + n;

    int nbuck = (n + NB - 1) / NB;
    int cap = (2 * (E / nbuck) + 1023) / 1024 * 1024;

    char* ws = (char*)d_ws;
    size_t off = 0;
    auto alloc = [&](size_t bytes) {
        void* p = ws + off;
        off += (bytes + 255) & ~(size_t)255;
        return p;
    };
    int*      rowp  = (int*)alloc((size_t)(n + 1) * 4);
    int*      csr   = (int*)alloc((size_t)etot * 4);
    __half*   h1h   = (__half*)alloc((size_t)n * 128 * 2);
    __half*   hmh   = (__half*)alloc((size_t)n * 128 * 2);
    float*    als1  = (float*)alloc((size_t)n * 4 * 4);
    float*    ald1  = (float*)alloc((size_t)n * 4 * 4);
    unsigned* gmaxu = (unsigned*)alloc(256);
    unsigned* gcnt  = (unsigned*)alloc((size_t)nbuck * 4);
    unsigned* gbase = (unsigned*)alloc((size_t)nbuck * 4);

    unsigned* binbuf = (unsigned*)h1h;   // CSR-build scratch overlays h1h
    __half* h2h = h1h;                   // layer-2 features overlay h1h
    float* als2 = als1;
    float* ald2 = ald1;

    int epb = (E + 1023) / 1024;

    k_init<<<1, 256, 0, stream>>>(gcnt, gmaxu, nbuck);
    k_bin<<<1024, 256, 0, stream>>>(src, dst, gcnt, binbuf, E, nbuck, cap, epb);
    k_bscan<<<1, 256, 0, stream>>>(gcnt, gbase, rowp, n, nbuck, etot);
    k_build<<<nbuck, 256, 0, stream>>>(gcnt, gbase, binbuf, rowp, csr, n, cap);

    k_gemm1<<<(n + 31) / 32, 256, 0, stream>>>(x, W1, as1, ad1, h1h, als1, ald1, n);
    k_gmax4<<<256, 256, 0, stream>>>((const float4*)als1, gmaxu, n);
    k_agg1<<<(n + 3) / 4, 256, 0, stream>>>(rowp, csr, als1, ald1, h1h, b1, gmaxu, hmh, n);

    k_gemm2<<<(n + 15) / 16, 640, 0, stream>>>(hmh, W2, as2, ad2, h2h, als2, ald2, n);
    k_gmax1<<<256, 256, 0, stream>>>(als2, gmaxu + 4, n);
    k_agg2<<<(n + 3) / 4, 256, 0, stream>>>(rowp, csr, als2, ald2, h2h, b2, gmaxu + 4, out, n);
}

// Round 16
// 362.179 us; speedup vs baseline: 1.1166x; 1.1166x over previous
//
#include <hip/hip_runtime.h>
#include <hip/hip_fp16.h>
#include <math.h>

// GAT node classification: 2 GATConv layers + ELU + log_softmax.
// N=100000, E=1600000 (+N self loops), IN=128, HEADS=4, HID=32, OUT=40.
//
// Rules learned:
//  - R4: every __shfl executes with ALL 64 lanes active; wave-uniform bounds;
//    predicate VALUES not control flow.
//  - R8: __shfl returns the SOURCE lane's evaluation of its operand; do
//    consumer-side selection AFTER the shfl.
//  - R9/R15: same-address atomics serialize at EVERY level (global: 25K
//    blocks ~280us; LDS: 40 writers/addr in gemm2 cost 127us). Reductions
//    with many colliding writers must use shfl/tree form.
//  - R10: diff-check unrolled FMA blocks line-by-line after mechanical edits.
//  - R12: 2-deep gather unroll is the sweet spot.
//  - R14: feature accumulation in packed fp16 (__hfma2); logits/dens f32.
//  - R16: al1 fused into gemm1 via 32-lane shfl reduce (no atomics) -- keeps
//    the win; al2 stays a standalone kernel.

#define SLOPE 0.2f
#define NB 512
#define NBSHIFT 9

#if defined(__has_builtin)
#if __has_builtin(__builtin_amdgcn_fdot2)
#define HAS_FDOT2 1
#endif
#endif

typedef _Float16 h2v __attribute__((ext_vector_type(2)));

__device__ __forceinline__ float dot2f(__half2 a, __half2 b, float c) {
#ifdef HAS_FDOT2
    return __builtin_amdgcn_fdot2(*reinterpret_cast<h2v*>(&a),
                                  *reinterpret_cast<h2v*>(&b), c, false);
#else
    float2 af = __half22float2(a), bf = __half22float2(b);
    return fmaf(af.y, bf.y, fmaf(af.x, bf.x, c));
#endif
}

__device__ __forceinline__ unsigned fenc(float f) {
    unsigned b = __float_as_uint(f);
    return (b & 0x80000000u) ? ~b : (b | 0x80000000u);
}
__device__ __forceinline__ float fdec(unsigned u) {
    return __uint_as_float((u & 0x80000000u) ? (u ^ 0x80000000u) : ~u);
}
__device__ __forceinline__ __half2 i2h2(int i) { return *reinterpret_cast<__half2*>(&i); }
__device__ __forceinline__ int h22i(__half2 h) { return *reinterpret_cast<int*>(&h); }
__device__ __forceinline__ __half2 h2shflxor(__half2 v, int off) {
    int j = __shfl_xor(h22i(v), off);
    return i2h2(j);
}

// ---------------- CSR construction (bucket sort) ----------------

__global__ __launch_bounds__(256) void k_init(unsigned* gcnt, unsigned* gmaxu, int nbuck) {
    int i = blockIdx.x * 256 + threadIdx.x;
    if (i < nbuck) gcnt[i] = 0u;
    if (i < 8) gmaxu[i] = 0u;   // enc(-huge)
}

__global__ __launch_bounds__(256) void k_bin(const int* __restrict__ src, const int* __restrict__ dst,
                                             unsigned* __restrict__ gcnt, unsigned* __restrict__ binbuf,
                                             int E, int nbuck, int cap, int epb) {
    __shared__ unsigned hist[256];
    __shared__ unsigned base[256];
    __shared__ unsigned cur[256];
    int t = threadIdx.x;
    if (t < nbuck) { hist[t] = 0u; cur[t] = 0u; }
    __syncthreads();
    int e0 = blockIdx.x * epb;
    int e1 = min(E, e0 + epb);
    for (int e = e0 + t; e < e1; e += 256) {
        int bk = dst[e] >> NBSHIFT;
        atomicAdd(&hist[bk], 1u);
    }
    __syncthreads();
    if (t < nbuck) base[t] = hist[t] ? atomicAdd(&gcnt[t], hist[t]) : 0u;
    __syncthreads();
    for (int e = e0 + t; e < e1; e += 256) {
        int d = dst[e];
        int bk = d >> NBSHIFT;
        unsigned p = atomicAdd(&cur[bk], 1u);
        binbuf[(size_t)bk * cap + base[bk] + p] =
            ((unsigned)src[e] << NBSHIFT) | (unsigned)(d & (NB - 1));
    }
}

__global__ __launch_bounds__(256) void k_bscan(const unsigned* __restrict__ gcnt, unsigned* __restrict__ gbase,
                                               int* __restrict__ row, int n, int nbuck, int etot) {
    __shared__ unsigned s[256];
    int t = threadIdx.x;
    unsigned v = 0u;
    if (t < nbuck) {
        int nodes = min(NB, n - t * NB);
        v = gcnt[t] + (unsigned)nodes;
    }
    s[t] = v;
    __syncthreads();
    for (int off = 1; off < 256; off <<= 1) {
        unsigned x = (t >= off) ? s[t - off] : 0u;
        __syncthreads();
        s[t] += x;
        __syncthreads();
    }
    if (t < nbuck) gbase[t] = s[t] - v;  // exclusive
    if (t == 0) row[n] = etot;
}

__global__ __launch_bounds__(256) void k_build(const unsigned* __restrict__ gcnt, const unsigned* __restrict__ gbase,
                                               const unsigned* __restrict__ binbuf, int* __restrict__ row,
                                               int* __restrict__ csr, int n, int cap) {
    __shared__ int s_cnt[NB];
    __shared__ int s_off[NB];
    __shared__ int sums[256];
    int b = blockIdx.x;
    int t = threadIdx.x;
    int nn = min(NB, n - b * NB);
    int total = (int)gcnt[b];
    int base = (int)gbase[b];
    s_cnt[t] = 0; s_cnt[t + 256] = 0;
    __syncthreads();
    const unsigned* rec = binbuf + (size_t)b * cap;
    for (int r = t; r < total; r += 256) atomicAdd(&s_cnt[rec[r] & (NB - 1)], 1);
    __syncthreads();
    int i0 = 2 * t, i1 = 2 * t + 1;
    int v0 = (i0 < nn) ? s_cnt[i0] + 1 : 0;
    int v1 = (i1 < nn) ? s_cnt[i1] + 1 : 0;
    int ps = v0 + v1;
    sums[t] = ps;
    __syncthreads();
    for (int off = 1; off < 256; off <<= 1) {
        int x = (t >= off) ? sums[t - off] : 0;
        __syncthreads();
        sums[t] += x;
        __syncthreads();
    }
    int ex = sums[t] - ps;
    s_off[i0] = ex;
    s_off[i1] = ex + v0;
    if (i0 < nn) { row[b * NB + i0] = base + ex;      csr[base + ex]      = b * NB + i0; }
    if (i1 < nn) { row[b * NB + i1] = base + ex + v0; csr[base + ex + v0] = b * NB + i1; }
    __syncthreads();
    s_cnt[t] = 1; s_cnt[t + 256] = 1;   // cursor: slot 0 = self loop
    __syncthreads();
    for (int r = t; r < total; r += 256) {
        unsigned rc = rec[r];
        int ld = rc & (NB - 1);
        int p = atomicAdd(&s_cnt[ld], 1);
        csr[base + s_off[ld] + p] = (int)(rc >> NBSHIFT);
    }
}

// ------- Layer 1 GEMM + fused al1: h1 = x @ W1, als/ald dots from f32 acc -------

__global__ __launch_bounds__(256) void k_gemm1(const float* __restrict__ x, const float* __restrict__ W,
                                               const float* __restrict__ asrc, const float* __restrict__ adst,
                                               __half* __restrict__ hh, float* __restrict__ als,
                                               float* __restrict__ ald, int n) {
    __shared__ __half2 xs2[32][64];     // [row][k2]
    __shared__ __half  wst[128][34];    // [c][kk] transposed W chunk; +2 pad
    int t = threadIdx.x;
    int row0 = blockIdx.x * 32;
#pragma unroll
    for (int i = 0; i < 4; i++) {
        int flat = t + 256 * i;
        int r = flat >> 5, c4 = flat & 31;
        int gr = row0 + r;
        float4 v = make_float4(0.f, 0.f, 0.f, 0.f);
        if (gr < n) v = ((const float4*)(x + (size_t)gr * 128))[c4];
        xs2[r][c4 * 2]     = __floats2half2_rn(v.x, v.y);
        xs2[r][c4 * 2 + 1] = __floats2half2_rn(v.z, v.w);
    }
    int ty = t >> 5;
    int tx = t & 31;
    float acc[4][4] = {};
    for (int kc = 0; kc < 4; ++kc) {
        __syncthreads();
#pragma unroll
        for (int i = 0; i < 4; i++) {
            int flat = t + 256 * i;
            int kk = flat >> 5, c4 = flat & 31;
            float4 v = ((const float4*)(W + (size_t)(kc * 32 + kk) * 128))[c4];
            wst[c4 * 4 + 0][kk] = __float2half_rn(v.x);
            wst[c4 * 4 + 1][kk] = __float2half_rn(v.y);
            wst[c4 * 4 + 2][kk] = __float2half_rn(v.z);
            wst[c4 * 4 + 3][kk] = __float2half_rn(v.w);
        }
        __syncthreads();
#pragma unroll
        for (int kk2 = 0; kk2 < 16; ++kk2) {
            __half2 wv[4];
#pragma unroll
            for (int j = 0; j < 4; j++)
                wv[j] = *(const __half2*)&wst[tx + 32 * j][kk2 * 2];
#pragma unroll
            for (int r = 0; r < 4; r++) {
                __half2 xv = xs2[ty + 8 * r][kc * 16 + kk2];
#pragma unroll
                for (int j = 0; j < 4; j++)
                    acc[r][j] = dot2f(xv, wv[j], acc[r][j]);
            }
        }
    }
    // per-head attention vectors: head j owns channel tx+32j -> a[j*32+tx]
    float vs0 = asrc[tx], vs1 = asrc[32 + tx], vs2 = asrc[64 + tx], vs3 = asrc[96 + tx];
    float vd0 = adst[tx], vd1 = adst[32 + tx], vd2 = adst[64 + tx], vd3 = adst[96 + tx];
#pragma unroll
    for (int r = 0; r < 4; r++) {
        int gr = row0 + ty + 8 * r;
        if (gr < n) {
#pragma unroll
            for (int j = 0; j < 4; j++)
                hh[(size_t)gr * 128 + tx + 32 * j] = __float2half_rn(acc[r][j]);
        }
        // fused al1: reduce over the 32-lane tx group (offsets 1..16 stay
        // inside the group; all 64 lanes execute -- R4). No atomics (R15).
        float ps0 = acc[r][0] * vs0, ps1 = acc[r][1] * vs1;
        float ps2 = acc[r][2] * vs2, ps3 = acc[r][3] * vs3;
        float pd0 = acc[r][0] * vd0, pd1 = acc[r][1] * vd1;
        float pd2 = acc[r][2] * vd2, pd3 = acc[r][3] * vd3;
#pragma unroll
        for (int off = 1; off <= 16; off <<= 1) {
            ps0 += __shfl_xor(ps0, off); ps1 += __shfl_xor(ps1, off);
            ps2 += __shfl_xor(ps2, off); ps3 += __shfl_xor(ps3, off);
            pd0 += __shfl_xor(pd0, off); pd1 += __shfl_xor(pd1, off);
            pd2 += __shfl_xor(pd2, off); pd3 += __shfl_xor(pd3, off);
        }
        if (tx == 0 && gr < n) {
            float4 s4 = make_float4(ps0, ps1, ps2, ps3);
            float4 d4 = make_float4(pd0, pd1, pd2, pd3);
            *(float4*)(als + (size_t)gr * 4) = s4;
            *(float4*)(ald + (size_t)gr * 4) = d4;
        }
    }
}

// global per-head max of als (256 blocks -> ~1K same-address atomics, OK)
__global__ __launch_bounds__(256) void k_gmax4(const float4* __restrict__ als4, unsigned* gm, int n) {
    float m0 = -INFINITY, m1 = -INFINITY, m2 = -INFINITY, m3 = -INFINITY;
    for (int i = blockIdx.x * 256 + threadIdx.x; i < n; i += 256 * 256) {
        float4 v = als4[i];
        m0 = fmaxf(m0, v.x); m1 = fmaxf(m1, v.y);
        m2 = fmaxf(m2, v.z); m3 = fmaxf(m3, v.w);
    }
#pragma unroll
    for (int off = 32; off; off >>= 1) {
        m0 = fmaxf(m0, __shfl_xor(m0, off));
        m1 = fmaxf(m1, __shfl_xor(m1, off));
        m2 = fmaxf(m2, __shfl_xor(m2, off));
        m3 = fmaxf(m3, __shfl_xor(m3, off));
    }
    __shared__ float sm[4][4];
    int wid = threadIdx.x >> 6;
    if ((threadIdx.x & 63) == 0) { sm[wid][0] = m0; sm[wid][1] = m1; sm[wid][2] = m2; sm[wid][3] = m3; }
    __syncthreads();
    if (threadIdx.x == 0) {
        float r0 = sm[0][0], r1 = sm[0][1], r2 = sm[0][2], r3 = sm[0][3];
        for (int w = 1; w < 4; w++) {
            r0 = fmaxf(r0, sm[w][0]); r1 = fmaxf(r1, sm[w][1]);
            r2 = fmaxf(r2, sm[w][2]); r3 = fmaxf(r3, sm[w][3]);
        }
        atomicMax(gm + 0, fenc(r0)); atomicMax(gm + 1, fenc(r1));
        atomicMax(gm + 2, fenc(r2)); atomicMax(gm + 3, fenc(r3));
    }
}

__global__ __launch_bounds__(256) void k_gmax1(const float* __restrict__ als, unsigned* gm, int n) {
    float m = -INFINITY;
    for (int i = blockIdx.x * 256 + threadIdx.x; i < n; i += 256 * 256) m = fmaxf(m, als[i]);
#pragma unroll
    for (int off = 32; off; off >>= 1) m = fmaxf(m, __shfl_xor(m, off));
    __shared__ float sm[4];
    int wid = threadIdx.x >> 6;
    if ((threadIdx.x & 63) == 0) sm[wid] = m;
    __syncthreads();
    if (threadIdx.x == 0)
        atomicMax(gm, fenc(fmaxf(fmaxf(sm[0], sm[1]), fmaxf(sm[2], sm[3]))));
}

// wave per dst node, single edge pass, prep-then-broadcast (2-deep, R12),
// packed fp16 accumulation (R14).
// Groups: g=lane>>4, lig=lane&15 (8 ch each), head=lig>>2.
__global__ __launch_bounds__(256) void k_agg1(const int* __restrict__ row, const int* __restrict__ csr,
                                              const float* __restrict__ als, const float* __restrict__ ald,
                                              const __half* __restrict__ h, const float* __restrict__ b,
                                              const unsigned* __restrict__ gmaxu, __half* __restrict__ out,
                                              int n) {
    int node = blockIdx.x * 4 + (threadIdx.x >> 6);
    if (node >= n) return;
    int lane = threadIdx.x & 63;
    int start = __builtin_amdgcn_readfirstlane(row[node]);
    int end   = __builtin_amdgcn_readfirstlane(row[node + 1]);

    int g = lane >> 4;
    int lig = lane & 15;
    int head = lig >> 2;

    float4 adv = *(const float4*)(ald + (size_t)node * 4);
    uint4 gu = *(const uint4*)gmaxu;
    float mt, mh0, mh1, mh2, mh3;
    mt = fdec(gu.x) + adv.x; mh0 = mt > 0.f ? mt : SLOPE * mt;
    mt = fdec(gu.y) + adv.y; mh1 = mt > 0.f ? mt : SLOPE * mt;
    mt = fdec(gu.z) + adv.z; mh2 = mt > 0.f ? mt : SLOPE * mt;
    mt = fdec(gu.w) + adv.w; mh3 = mt > 0.f ? mt : SLOPE * mt;

    const __half2 z2 = __floats2half2_rn(0.f, 0.f);
    float den0 = 0.f, den1 = 0.f, den2 = 0.f, den3 = 0.f;
    __half2 ah0 = z2, ah1 = z2, ah2 = z2, ah3 = z2;   // 8 fp16 channel accumulators

    for (int k0 = start; k0 < end; k0 += 64) {
        int nb = end - k0; if (nb > 64) nb = 64;
        // ---- prep: this lane's edge -> 4 exps, pack to 2x half2 ----
        int s_l = (lane < nb) ? csr[k0 + lane] : 0;
        float4 av = *(const float4*)(als + (size_t)s_l * 4);
        float e, x0, x1, x2, x3;
        e = av.x + adv.x; e = e > 0.f ? e : SLOPE * e; x0 = __expf(e - mh0);
        e = av.y + adv.y; e = e > 0.f ? e : SLOPE * e; x1 = __expf(e - mh1);
        e = av.z + adv.z; e = e > 0.f ? e : SLOPE * e; x2 = __expf(e - mh2);
        e = av.w + adv.w; e = e > 0.f ? e : SLOPE * e; x3 = __expf(e - mh3);
        bool valid = lane < nb;
        x0 = valid ? x0 : 0.f; x1 = valid ? x1 : 0.f;
        x2 = valid ? x2 : 0.f; x3 = valid ? x3 : 0.f;
        den0 += x0; den1 += x1; den2 += x2; den3 += x3;
        __half2 p01 = __floats2half2_rn(x0, x1);
        __half2 p23 = __floats2half2_rn(x2, x3);
        int w01 = h22i(p01);
        int w23 = h22i(p23);

        // ---- gather: 8 edges per unrolled iter (4 groups x 2) ----
        for (int jj = 0; jj < nb; jj += 8) {
            int eA = jj + g;        // <= 63
            int eB = jj + 4 + g;    // <= 63
            int sA = __shfl(s_l, eA);
            int sB = __shfl(s_l, eB);
            // R8 rule: shfl RAW words; select by THIS lane's head afterwards.
            int wA01 = __shfl(w01, eA);
            int wA23 = __shfl(w23, eA);
            int wB01 = __shfl(w01, eB);
            int wB23 = __shfl(w23, eB);
            int wA = (head & 2) ? wA23 : wA01;
            int wB = (head & 2) ? wB23 : wB01;
            uint4 hvA = *(const uint4*)(h + ((size_t)sA << 7) + lig * 8);
            uint4 hvB = *(const uint4*)(h + ((size_t)sB << 7) + lig * 8);
            __half exhA = (head & 1) ? __high2half(i2h2(wA)) : __low2half(i2h2(wA));
            __half exhB = (head & 1) ? __high2half(i2h2(wB)) : __low2half(i2h2(wB));
            __half2 exA2 = __half2half2(exhA);
            __half2 exB2 = __half2half2(exhB);
            exA2 = (eA < nb) ? exA2 : z2;   // value-predicate (R4)
            exB2 = (eB < nb) ? exB2 : z2;
            ah0 = __hfma2(exA2, i2h2((int)hvA.x), ah0);
            ah1 = __hfma2(exA2, i2h2((int)hvA.y), ah1);
            ah2 = __hfma2(exA2, i2h2((int)hvA.z), ah2);
            ah3 = __hfma2(exA2, i2h2((int)hvA.w), ah3);
            ah0 = __hfma2(exB2, i2h2((int)hvB.x), ah0);
            ah1 = __hfma2(exB2, i2h2((int)hvB.y), ah1);
            ah2 = __hfma2(exB2, i2h2((int)hvB.z), ah2);
            ah3 = __hfma2(exB2, i2h2((int)hvB.w), ah3);
        }
    }
    // den: full 64-lane xor reduce (per-lane partials)
#pragma unroll
    for (int off = 32; off; off >>= 1) {
        den0 += __shfl_xor(den0, off);
        den1 += __shfl_xor(den1, off);
        den2 += __shfl_xor(den2, off);
        den3 += __shfl_xor(den3, off);
    }
    // accs: combine 4 groups (xor 16, 32) in packed fp16
    ah0 = __hadd2(ah0, h2shflxor(ah0, 16));
    ah1 = __hadd2(ah1, h2shflxor(ah1, 16));
    ah2 = __hadd2(ah2, h2shflxor(ah2, 16));
    ah3 = __hadd2(ah3, h2shflxor(ah3, 16));
    ah0 = __hadd2(ah0, h2shflxor(ah0, 32));
    ah1 = __hadd2(ah1, h2shflxor(ah1, 32));
    ah2 = __hadd2(ah2, h2shflxor(ah2, 32));
    ah3 = __hadd2(ah3, h2shflxor(ah3, 32));
    if (g == 0) {
        float den_h = (head & 2) ? ((head & 1) ? den3 : den2) : ((head & 1) ? den1 : den0);
        float inv = 1.f / den_h;
        float2 f0 = __half22float2(ah0);
        float2 f1 = __half22float2(ah1);
        float2 f2 = __half22float2(ah2);
        float2 f3 = __half22float2(ah3);
        float4 bv0 = *(const float4*)(b + lig * 8);
        float4 bv1 = *(const float4*)(b + lig * 8 + 4);
        float o0, o1, o2, o3, o4, o5, o6, o7;
        o0 = f0.x * inv + bv0.x; o0 = o0 > 0.f ? o0 : expm1f(o0);
        o1 = f0.y * inv + bv0.y; o1 = o1 > 0.f ? o1 : expm1f(o1);
        o2 = f1.x * inv + bv0.z; o2 = o2 > 0.f ? o2 : expm1f(o2);
        o3 = f1.y * inv + bv0.w; o3 = o3 > 0.f ? o3 : expm1f(o3);
        o4 = f2.x * inv + bv1.x; o4 = o4 > 0.f ? o4 : expm1f(o4);
        o5 = f2.y * inv + bv1.y; o5 = o5 > 0.f ? o5 : expm1f(o5);
        o6 = f3.x * inv + bv1.z; o6 = o6 > 0.f ? o6 : expm1f(o6);
        o7 = f3.y * inv + bv1.w; o7 = o7 > 0.f ? o7 : expm1f(o7);
        __half2 q0 = __floats2half2_rn(o0, o1);
        __half2 q1 = __floats2half2_rn(o2, o3);
        __half2 q2 = __floats2half2_rn(o4, o5);
        __half2 q3 = __floats2half2_rn(o6, o7);
        uint4 st;
        st.x = (unsigned)h22i(q0);
        st.y = (unsigned)h22i(q1);
        st.z = (unsigned)h22i(q2);
        st.w = (unsigned)h22i(q3);
        *(uint4*)(out + ((size_t)node << 7) + lig * 8) = st;
    }
}

// ------- Layer 2 GEMM: h2 = hm(fp16) @ W2 (128->40), fp16 out (R14 form) -------

__global__ __launch_bounds__(640) void k_gemm2(const __half* __restrict__ hm, const float* __restrict__ W2,
                                               __half* __restrict__ h2h, int n) {
    __shared__ float xs[16][128];
    __shared__ float ws[128 * 40];
    int t = threadIdx.x;
    int row0 = blockIdx.x * 16;
    for (int i = t; i < 128 * 40; i += 640) ws[i] = W2[i];
    if (t < 256) {
        int r = t >> 4, c8 = t & 15;
        int gr = row0 + r;
        float* d = &xs[r][c8 * 8];
        if (gr < n) {
            uint4 v = *(const uint4*)(hm + (size_t)gr * 128 + c8 * 8);
            float2 f0 = __half22float2(*reinterpret_cast<__half2*>(&v.x));
            float2 f1 = __half22float2(*reinterpret_cast<__half2*>(&v.y));
            float2 f2 = __half22float2(*reinterpret_cast<__half2*>(&v.z));
            float2 f3 = __half22float2(*reinterpret_cast<__half2*>(&v.w));
            d[0] = f0.x; d[1] = f0.y; d[2] = f1.x; d[3] = f1.y;
            d[4] = f2.x; d[5] = f2.y; d[6] = f3.x; d[7] = f3.y;
        } else {
            for (int j = 0; j < 8; j++) d[j] = 0.f;
        }
    }
    __syncthreads();
    int r = t / 40, c = t - r * 40;
    int gr = row0 + r;
    float acc = 0.f;
#pragma unroll 8
    for (int k = 0; k < 128; ++k) acc += xs[r][k] * ws[k * 40 + c];
    if (gr < n) h2h[(size_t)gr * 40 + c] = __float2half_rn(acc);
}

// wave per node; lanes 0-19 load 2 ch each (no atomics).
__global__ __launch_bounds__(256) void k_al2(const __half* __restrict__ h2, const float* __restrict__ a_s,
                                             const float* __restrict__ a_d, float* als, float* ald, int n) {
    int t = threadIdx.x;
    int node = blockIdx.x * 4 + (t >> 6);
    int l = t & 63;
    if (node >= n) return;
    float ps = 0.f, pd = 0.f;
    if (l < 20) {
        unsigned hv = *(const unsigned*)(h2 + (size_t)node * 40 + l * 2);
        float2 f = __half22float2(*reinterpret_cast<__half2*>(&hv));
        float2 vs = *(const float2*)(a_s + l * 2);
        float2 vd = *(const float2*)(a_d + l * 2);
        ps = f.x * vs.x + f.y * vs.y;
        pd = f.x * vd.x + f.y * vd.y;
    }
#pragma unroll
    for (int off = 32; off; off >>= 1) { ps += __shfl_xor(ps, off); pd += __shfl_xor(pd, off); }
    if (l == 0) { als[node] = ps; ald[node] = pd; }
}

// wave per node, single edge pass + log_softmax (2-deep, packed fp16 acc).
// Groups: g=lane/5 (12 edges in flight), lig=lane-5g (8 ch each); g==12 idle.
__global__ __launch_bounds__(256) void k_agg2(const int* __restrict__ row, const int* __restrict__ csr,
                                              const float* __restrict__ als, const float* __restrict__ ald,
                                              const __half* __restrict__ h2, const float* __restrict__ b2,
                                              const unsigned* __restrict__ gmaxu, float* __restrict__ out,
                                              int n) {
    int node = blockIdx.x * 4 + (threadIdx.x >> 6);
    if (node >= n) return;
    int lane = threadIdx.x & 63;
    int start = __builtin_amdgcn_readfirstlane(row[node]);
    int end   = __builtin_amdgcn_readfirstlane(row[node + 1]);
    float ad = ald[node];
    float mt = fdec(gmaxu[0]) + ad;
    float mh = mt > 0.f ? mt : SLOPE * mt;

    int g = lane / 5;
    int lig = lane - g * 5;
    bool act = g < 12;

    const __half2 z2 = __floats2half2_rn(0.f, 0.f);
    float den = 0.f;
    __half2 ah0 = z2, ah1 = z2, ah2 = z2, ah3 = z2;
    for (int k0 = start; k0 < end; k0 += 64) {
        int nb = end - k0; if (nb > 64) nb = 64;
        int s_l = (lane < nb) ? csr[k0 + lane] : 0;
        float e = als[s_l] + ad; e = e > 0.f ? e : SLOPE * e;
        float ex_l = __expf(e - mh);
        ex_l = (lane < nb) ? ex_l : 0.f;
        den += ex_l;
        __half exh_l = __float2half_rn(ex_l);
        int exi_l = h22i(__half2half2(exh_l));   // replicated half2

        for (int jj = 0; jj < nb; jj += 24) {
            int eA = jj + g;         // may exceed 63 -> mask + predicate
            int eB = jj + 12 + g;
            int sA = __shfl(s_l, eA & 63);
            int sB = __shfl(s_l, eB & 63);
            int exAi = __shfl(exi_l, eA & 63);
            int exBi = __shfl(exi_l, eB & 63);
            uint4 hvA = *(const uint4*)(h2 + (size_t)sA * 40 + lig * 8);
            uint4 hvB = *(const uint4*)(h2 + (size_t)sB * 40 + lig * 8);
            __half2 exA2 = i2h2(exAi);
            __half2 exB2 = i2h2(exBi);
            exA2 = (act && eA < nb) ? exA2 : z2;
            exB2 = (act && eB < nb) ? exB2 : z2;
            ah0 = __hfma2(exA2, i2h2((int)hvA.x), ah0);
            ah1 = __hfma2(exA2, i2h2((int)hvA.y), ah1);
            ah2 = __hfma2(exA2, i2h2((int)hvA.z), ah2);
            ah3 = __hfma2(exA2, i2h2((int)hvA.w), ah3);
            ah0 = __hfma2(exB2, i2h2((int)hvB.x), ah0);
            ah1 = __hfma2(exB2, i2h2((int)hvB.y), ah1);
            ah2 = __hfma2(exB2, i2h2((int)hvB.z), ah2);
            ah3 = __hfma2(exB2, i2h2((int)hvB.w), ah3);
        }
    }
    // den: full 64-lane xor reduce
#pragma unroll
    for (int off = 32; off; off >>= 1) den += __shfl_xor(den, off);
    // accs: combine 12 groups of 5 -> lanes 0-4 (packed fp16)
    int t1i;
    t1i = __shfl(h22i(ah0), (lane + 30) & 63); ah0 = __hadd2(ah0, i2h2(t1i));
    t1i = __shfl(h22i(ah1), (lane + 30) & 63); ah1 = __hadd2(ah1, i2h2(t1i));
    t1i = __shfl(h22i(ah2), (lane + 30) & 63); ah2 = __hadd2(ah2, i2h2(t1i));
    t1i = __shfl(h22i(ah3), (lane + 30) & 63); ah3 = __hadd2(ah3, i2h2(t1i));
    t1i = __shfl(h22i(ah0), (lane + 15) & 63); ah0 = __hadd2(ah0, i2h2(t1i));
    t1i = __shfl(h22i(ah1), (lane + 15) & 63); ah1 = __hadd2(ah1, i2h2(t1i));
    t1i = __shfl(h22i(ah2), (lane + 15) & 63); ah2 = __hadd2(ah2, i2h2(t1i));
    t1i = __shfl(h22i(ah3), (lane + 15) & 63); ah3 = __hadd2(ah3, i2h2(t1i));
    int t2i;
    t1i = __shfl(h22i(ah0), (lane + 5) & 63); t2i = __shfl(h22i(ah0), (lane + 10) & 63);
    ah0 = __hadd2(__hadd2(ah0, i2h2(t1i)), i2h2(t2i));
    t1i = __shfl(h22i(ah1), (lane + 5) & 63); t2i = __shfl(h22i(ah1), (lane + 10) & 63);
    ah1 = __hadd2(__hadd2(ah1, i2h2(t1i)), i2h2(t2i));
    t1i = __shfl(h22i(ah2), (lane + 5) & 63); t2i = __shfl(h22i(ah2), (lane + 10) & 63);
    ah2 = __hadd2(__hadd2(ah2, i2h2(t1i)), i2h2(t2i));
    t1i = __shfl(h22i(ah3), (lane + 5) & 63); t2i = __shfl(h22i(ah3), (lane + 10) & 63);
    ah3 = __hadd2(__hadd2(ah3, i2h2(t1i)), i2h2(t2i));

    // log_softmax epilogue: lanes 0-4 hold ch lane*8..+7
    float v0 = 0.f, v1 = 0.f, v2 = 0.f, v3 = 0.f, v4 = 0.f, v5 = 0.f, v6 = 0.f, v7 = 0.f;
    float mv = -INFINITY;
    if (lane < 5) {
        float inv = 1.f / den;
        float2 f0 = __half22float2(ah0);
        float2 f1 = __half22float2(ah1);
        float2 f2 = __half22float2(ah2);
        float2 f3 = __half22float2(ah3);
        float4 bv0 = *(const float4*)(b2 + lane * 8);
        float4 bv1 = *(const float4*)(b2 + lane * 8 + 4);
        v0 = f0.x * inv + bv0.x; v1 = f0.y * inv + bv0.y;
        v2 = f1.x * inv + bv0.z; v3 = f1.y * inv + bv0.w;
        v4 = f2.x * inv + bv1.x; v5 = f2.y * inv + bv1.y;
        v6 = f3.x * inv + bv1.z; v7 = f3.y * inv + bv1.w;
        mv = fmaxf(fmaxf(fmaxf(v0, v1), fmaxf(v2, v3)),
                   fmaxf(fmaxf(v4, v5), fmaxf(v6, v7)));
    }
#pragma unroll
    for (int off = 32; off; off >>= 1) mv = fmaxf(mv, __shfl_xor(mv, off));
    float se = 0.f;
    if (lane < 5)
        se = __expf(v0 - mv) + __expf(v1 - mv) + __expf(v2 - mv) + __expf(v3 - mv)
           + __expf(v4 - mv) + __expf(v5 - mv) + __expf(v6 - mv) + __expf(v7 - mv);
#pragma unroll
    for (int off = 32; off; off >>= 1) se += __shfl_xor(se, off);
    if (lane < 5) {
        float lse = mv + __logf(se);
        float4 o0, o1;
        o0.x = v0 - lse; o0.y = v1 - lse; o0.z = v2 - lse; o0.w = v3 - lse;
        o1.x = v4 - lse; o1.y = v5 - lse; o1.z = v6 - lse; o1.w = v7 - lse;
        *(float4*)(out + (size_t)node * 40 + lane * 8) = o0;
        *(float4*)(out + (size_t)node * 40 + lane * 8 + 4) = o1;
    }
}

// ---------------- launch ----------------

extern "C" void kernel_launch(void* const* d_in, const int* in_sizes, int n_in,
                              void* d_out, int out_size, void* d_ws, size_t ws_size,
                              hipStream_t stream) {
    const float* x   = (const float*)d_in[0];
    const int*   ei  = (const int*)d_in[1];
    const float* W1  = (const float*)d_in[2];
    const float* as1 = (const float*)d_in[3];
    const float* ad1 = (const float*)d_in[4];
    const float* b1  = (const float*)d_in[5];
    const float* W2  = (const float*)d_in[6];
    const float* as2 = (const float*)d_in[7];
    const float* ad2 = (const float*)d_in[8];
    const float* b2  = (const float*)d_in[9];
    float* out = (float*)d_out;

    int n = in_sizes[0] / 128;
    int E = in_sizes[1] / 2;
    const int* src = ei;
    const int* dst = ei + E;
    int etot = E + n;

    int nbuck = (n + NB - 1) / NB;
    int cap = (2 * (E / nbuck) + 1023) / 1024 * 1024;

    char* ws = (char*)d_ws;
    size_t off = 0;
    auto alloc = [&](size_t bytes) {
        void* p = ws + off;
        off += (bytes + 255) & ~(size_t)255;
        return p;
    };
    int*      rowp  = (int*)alloc((size_t)(n + 1) * 4);
    int*      csr   = (int*)alloc((size_t)etot * 4);
    __half*   h1h   = (__half*)alloc((size_t)n * 128 * 2);
    __half*   hmh   = (__half*)alloc((size_t)n * 128 * 2);
    float*    als1  = (float*)alloc((size_t)n * 4 * 4);
    float*    ald1  = (float*)alloc((size_t)n * 4 * 4);
    unsigned* gmaxu = (unsigned*)alloc(256);
    unsigned* gcnt  = (unsigned*)alloc((size_t)nbuck * 4);
    unsigned* gbase = (unsigned*)alloc((size_t)nbuck * 4);

    unsigned* binbuf = (unsigned*)h1h;   // CSR-build scratch overlays h1h
    __half* h2h = h1h;                   // layer-2 features overlay h1h
    float* als2 = als1;
    float* ald2 = ald1;

    int epb = (E + 1023) / 1024;

    k_init<<<1, 256, 0, stream>>>(gcnt, gmaxu, nbuck);
    k_bin<<<1024, 256, 0, stream>>>(src, dst, gcnt, binbuf, E, nbuck, cap, epb);
    k_bscan<<<1, 256, 0, stream>>>(gcnt, gbase, rowp, n, nbuck, etot);
    k_build<<<nbuck, 256, 0, stream>>>(gcnt, gbase, binbuf, rowp, csr, n, cap);

    k_gemm1<<<(n + 31) / 32, 256, 0, stream>>>(x, W1, as1, ad1, h1h, als1, ald1, n);
    k_gmax4<<<256, 256, 0, stream>>>((const float4*)als1, gmaxu, n);
    k_agg1<<<(n + 3) / 4, 256, 0, stream>>>(rowp, csr, als1, ald1, h1h, b1, gmaxu, hmh, n);

    k_gemm2<<<(n + 15) / 16, 640, 0, stream>>>(hmh, W2, h2h, n);
    k_al2<<<(n + 3) / 4, 256, 0, stream>>>(h2h, as2, ad2, als2, ald2, n);
    k_gmax1<<<256, 256, 0, stream>>>(als2, gmaxu + 4, n);
    k_agg2<<<(n + 3) / 4, 256, 0, stream>>>(rowp, csr, als2, ald2, h2h, b2, gmaxu + 4, out, n);
}

// Round 17
// 356.964 us; speedup vs baseline: 1.1329x; 1.0146x over previous
//
#include <hip/hip_runtime.h>
#include <hip/hip_fp16.h>
#include <math.h>

// GAT node classification: 2 GATConv layers + ELU + log_softmax.
// N=100000, E=1600000 (+N self loops), IN=128, HEADS=4, HID=32, OUT=40.
//
// Rules learned:
//  - R4: every __shfl executes with ALL 64 lanes active; wave-uniform bounds;
//    predicate VALUES not control flow.
//  - R8: __shfl returns the SOURCE lane's evaluation of its operand.
//  - R9/R15: same-address atomics serialize at every level; many-writer
//    reductions must be shfl/tree form.
//  - R10: diff-check unrolled blocks line-by-line after mechanical edits.
//  - R12: 2-deep gather unroll is the sweet spot.
//  - R14: feature accumulation in packed fp16 (__hfma2); logits/dens f32.
//  - R17: independent kernels grid-fused (block-range dispatch) to overlap
//    CSR build with GEMM1 and bscan with gmax4; k_init -> hipMemsetAsync.

#define SLOPE 0.2f
#define NB 512
#define NBSHIFT 9

#if defined(__has_builtin)
#if __has_builtin(__builtin_amdgcn_fdot2)
#define HAS_FDOT2 1
#endif
#endif

typedef _Float16 h2v __attribute__((ext_vector_type(2)));

__device__ __forceinline__ float dot2f(__half2 a, __half2 b, float c) {
#ifdef HAS_FDOT2
    return __builtin_amdgcn_fdot2(*reinterpret_cast<h2v*>(&a),
                                  *reinterpret_cast<h2v*>(&b), c, false);
#else
    float2 af = __half22float2(a), bf = __half22float2(b);
    return fmaf(af.y, bf.y, fmaf(af.x, bf.x, c));
#endif
}

__device__ __forceinline__ unsigned fenc(float f) {
    unsigned b = __float_as_uint(f);
    return (b & 0x80000000u) ? ~b : (b | 0x80000000u);
}
__device__ __forceinline__ float fdec(unsigned u) {
    return __uint_as_float((u & 0x80000000u) ? (u ^ 0x80000000u) : ~u);
}
__device__ __forceinline__ __half2 i2h2(int i) { return *reinterpret_cast<__half2*>(&i); }
__device__ __forceinline__ int h22i(__half2 h) { return *reinterpret_cast<int*>(&h); }
__device__ __forceinline__ __half2 h2shflxor(__half2 v, int off) {
    int j = __shfl_xor(h22i(v), off);
    return i2h2(j);
}

// ---------------- CSR bin (device body) ----------------

__device__ void bin_body(const int* __restrict__ src, const int* __restrict__ dst,
                         unsigned* __restrict__ gcnt, unsigned* __restrict__ binbuf,
                         int E, int nbuck, int cap, int epb, int bid) {
    __shared__ unsigned hist[256];
    __shared__ unsigned base[256];
    __shared__ unsigned cur[256];
    int t = threadIdx.x;
    if (t < nbuck) { hist[t] = 0u; cur[t] = 0u; }
    __syncthreads();
    int e0 = bid * epb;
    int e1 = min(E, e0 + epb);
    for (int e = e0 + t; e < e1; e += 256) {
        int bk = dst[e] >> NBSHIFT;
        atomicAdd(&hist[bk], 1u);
    }
    __syncthreads();
    if (t < nbuck) base[t] = hist[t] ? atomicAdd(&gcnt[t], hist[t]) : 0u;
    __syncthreads();
    for (int e = e0 + t; e < e1; e += 256) {
        int d = dst[e];
        int bk = d >> NBSHIFT;
        unsigned p = atomicAdd(&cur[bk], 1u);
        binbuf[(size_t)bk * cap + base[bk] + p] =
            ((unsigned)src[e] << NBSHIFT) | (unsigned)(d & (NB - 1));
    }
}

// ---------------- Layer1 GEMM + fused al1 (device body) ----------------

__device__ void gemm1_body(const float* __restrict__ x, const float* __restrict__ W,
                           const float* __restrict__ asrc, const float* __restrict__ adst,
                           __half* __restrict__ hh, float* __restrict__ als,
                           float* __restrict__ ald, int n, int bid) {
    __shared__ __half2 xs2[32][64];     // [row][k2]
    __shared__ __half  wst[128][34];    // [c][kk] transposed W chunk; +2 pad
    int t = threadIdx.x;
    int row0 = bid * 32;
#pragma unroll
    for (int i = 0; i < 4; i++) {
        int flat = t + 256 * i;
        int r = flat >> 5, c4 = flat & 31;
        int gr = row0 + r;
        float4 v = make_float4(0.f, 0.f, 0.f, 0.f);
        if (gr < n) v = ((const float4*)(x + (size_t)gr * 128))[c4];
        xs2[r][c4 * 2]     = __floats2half2_rn(v.x, v.y);
        xs2[r][c4 * 2 + 1] = __floats2half2_rn(v.z, v.w);
    }
    int ty = t >> 5;
    int tx = t & 31;
    float acc[4][4] = {};
    for (int kc = 0; kc < 4; ++kc) {
        __syncthreads();
#pragma unroll
        for (int i = 0; i < 4; i++) {
            int flat = t + 256 * i;
            int kk = flat >> 5, c4 = flat & 31;
            float4 v = ((const float4*)(W + (size_t)(kc * 32 + kk) * 128))[c4];
            wst[c4 * 4 + 0][kk] = __float2half_rn(v.x);
            wst[c4 * 4 + 1][kk] = __float2half_rn(v.y);
            wst[c4 * 4 + 2][kk] = __float2half_rn(v.z);
            wst[c4 * 4 + 3][kk] = __float2half_rn(v.w);
        }
        __syncthreads();
#pragma unroll
        for (int kk2 = 0; kk2 < 16; ++kk2) {
            __half2 wv[4];
#pragma unroll
            for (int j = 0; j < 4; j++)
                wv[j] = *(const __half2*)&wst[tx + 32 * j][kk2 * 2];
#pragma unroll
            for (int r = 0; r < 4; r++) {
                __half2 xv = xs2[ty + 8 * r][kc * 16 + kk2];
#pragma unroll
                for (int j = 0; j < 4; j++)
                    acc[r][j] = dot2f(xv, wv[j], acc[r][j]);
            }
        }
    }
    float vs0 = asrc[tx], vs1 = asrc[32 + tx], vs2 = asrc[64 + tx], vs3 = asrc[96 + tx];
    float vd0 = adst[tx], vd1 = adst[32 + tx], vd2 = adst[64 + tx], vd3 = adst[96 + tx];
#pragma unroll
    for (int r = 0; r < 4; r++) {
        int gr = row0 + ty + 8 * r;
        if (gr < n) {
#pragma unroll
            for (int j = 0; j < 4; j++)
                hh[(size_t)gr * 128 + tx + 32 * j] = __float2half_rn(acc[r][j]);
        }
        // fused al1: 32-lane shfl reduce (no atomics -- R15); all lanes run.
        float ps0 = acc[r][0] * vs0, ps1 = acc[r][1] * vs1;
        float ps2 = acc[r][2] * vs2, ps3 = acc[r][3] * vs3;
        float pd0 = acc[r][0] * vd0, pd1 = acc[r][1] * vd1;
        float pd2 = acc[r][2] * vd2, pd3 = acc[r][3] * vd3;
#pragma unroll
        for (int off = 1; off <= 16; off <<= 1) {
            ps0 += __shfl_xor(ps0, off); ps1 += __shfl_xor(ps1, off);
            ps2 += __shfl_xor(ps2, off); ps3 += __shfl_xor(ps3, off);
            pd0 += __shfl_xor(pd0, off); pd1 += __shfl_xor(pd1, off);
            pd2 += __shfl_xor(pd2, off); pd3 += __shfl_xor(pd3, off);
        }
        if (tx == 0 && gr < n) {
            float4 s4 = make_float4(ps0, ps1, ps2, ps3);
            float4 d4 = make_float4(pd0, pd1, pd2, pd3);
            *(float4*)(als + (size_t)gr * 4) = s4;
            *(float4*)(ald + (size_t)gr * 4) = d4;
        }
    }
}

// fused: blocks [0,binBlocks) bin; [binBlocks, ...) gemm1
__global__ __launch_bounds__(256) void k_binGemm1(const int* src, const int* dst,
                                                  unsigned* gcnt, unsigned* binbuf,
                                                  int E, int nbuck, int cap, int epb, int binBlocks,
                                                  const float* x, const float* W,
                                                  const float* asrc, const float* adst,
                                                  __half* hh, float* als, float* ald, int n) {
    if ((int)blockIdx.x < binBlocks)
        bin_body(src, dst, gcnt, binbuf, E, nbuck, cap, epb, blockIdx.x);
    else
        gemm1_body(x, W, asrc, adst, hh, als, ald, n, blockIdx.x - binBlocks);
}

// ---------------- bscan (device body) ----------------

__device__ void bscan_body(const unsigned* __restrict__ gcnt, unsigned* __restrict__ gbase,
                           int* __restrict__ row, int n, int nbuck, int etot) {
    __shared__ unsigned s[256];
    int t = threadIdx.x;
    unsigned v = 0u;
    if (t < nbuck) {
        int nodes = min(NB, n - t * NB);
        v = gcnt[t] + (unsigned)nodes;
    }
    s[t] = v;
    __syncthreads();
    for (int off = 1; off < 256; off <<= 1) {
        unsigned x = (t >= off) ? s[t - off] : 0u;
        __syncthreads();
        s[t] += x;
        __syncthreads();
    }
    if (t < nbuck) gbase[t] = s[t] - v;  // exclusive
    if (t == 0) row[n] = etot;
}

__device__ void gmax4_body(const float4* __restrict__ als4, unsigned* gm, int n, int bid) {
    float m0 = -INFINITY, m1 = -INFINITY, m2 = -INFINITY, m3 = -INFINITY;
    for (int i = bid * 256 + threadIdx.x; i < n; i += 256 * 256) {
        float4 v = als4[i];
        m0 = fmaxf(m0, v.x); m1 = fmaxf(m1, v.y);
        m2 = fmaxf(m2, v.z); m3 = fmaxf(m3, v.w);
    }
#pragma unroll
    for (int off = 32; off; off >>= 1) {
        m0 = fmaxf(m0, __shfl_xor(m0, off));
        m1 = fmaxf(m1, __shfl_xor(m1, off));
        m2 = fmaxf(m2, __shfl_xor(m2, off));
        m3 = fmaxf(m3, __shfl_xor(m3, off));
    }
    __shared__ float sm[4][4];
    int wid = threadIdx.x >> 6;
    if ((threadIdx.x & 63) == 0) { sm[wid][0] = m0; sm[wid][1] = m1; sm[wid][2] = m2; sm[wid][3] = m3; }
    __syncthreads();
    if (threadIdx.x == 0) {
        float r0 = sm[0][0], r1 = sm[0][1], r2 = sm[0][2], r3 = sm[0][3];
        for (int w = 1; w < 4; w++) {
            r0 = fmaxf(r0, sm[w][0]); r1 = fmaxf(r1, sm[w][1]);
            r2 = fmaxf(r2, sm[w][2]); r3 = fmaxf(r3, sm[w][3]);
        }
        atomicMax(gm + 0, fenc(r0)); atomicMax(gm + 1, fenc(r1));
        atomicMax(gm + 2, fenc(r2)); atomicMax(gm + 3, fenc(r3));
    }
}

// fused: block 0 bscan; blocks [1,257) gmax4
__global__ __launch_bounds__(256) void k_bscanGmax4(const unsigned* gcnt, unsigned* gbase,
                                                    int* row, int n, int nbuck, int etot,
                                                    const float4* als4, unsigned* gm) {
    if (blockIdx.x == 0)
        bscan_body(gcnt, gbase, row, n, nbuck, etot);
    else
        gmax4_body(als4, gm, n, blockIdx.x - 1);
}

__global__ __launch_bounds__(256) void k_build(const unsigned* __restrict__ gcnt, const unsigned* __restrict__ gbase,
                                               const unsigned* __restrict__ binbuf, int* __restrict__ row,
                                               int* __restrict__ csr, int n, int cap) {
    __shared__ int s_cnt[NB];
    __shared__ int s_off[NB];
    __shared__ int sums[256];
    int b = blockIdx.x;
    int t = threadIdx.x;
    int nn = min(NB, n - b * NB);
    int total = (int)gcnt[b];
    int base = (int)gbase[b];
    s_cnt[t] = 0; s_cnt[t + 256] = 0;
    __syncthreads();
    const unsigned* rec = binbuf + (size_t)b * cap;
    for (int r = t; r < total; r += 256) atomicAdd(&s_cnt[rec[r] & (NB - 1)], 1);
    __syncthreads();
    int i0 = 2 * t, i1 = 2 * t + 1;
    int v0 = (i0 < nn) ? s_cnt[i0] + 1 : 0;
    int v1 = (i1 < nn) ? s_cnt[i1] + 1 : 0;
    int ps = v0 + v1;
    sums[t] = ps;
    __syncthreads();
    for (int off = 1; off < 256; off <<= 1) {
        int x = (t >= off) ? sums[t - off] : 0;
        __syncthreads();
        sums[t] += x;
        __syncthreads();
    }
    int ex = sums[t] - ps;
    s_off[i0] = ex;
    s_off[i1] = ex + v0;
    if (i0 < nn) { row[b * NB + i0] = base + ex;      csr[base + ex]      = b * NB + i0; }
    if (i1 < nn) { row[b * NB + i1] = base + ex + v0; csr[base + ex + v0] = b * NB + i1; }
    __syncthreads();
    s_cnt[t] = 1; s_cnt[t + 256] = 1;   // cursor: slot 0 = self loop
    __syncthreads();
    for (int r = t; r < total; r += 256) {
        unsigned rc = rec[r];
        int ld = rc & (NB - 1);
        int p = atomicAdd(&s_cnt[ld], 1);
        csr[base + s_off[ld] + p] = (int)(rc >> NBSHIFT);
    }
}

__global__ __launch_bounds__(256) void k_gmax1(const float* __restrict__ als, unsigned* gm, int n) {
    float m = -INFINITY;
    for (int i = blockIdx.x * 256 + threadIdx.x; i < n; i += 256 * 256) m = fmaxf(m, als[i]);
#pragma unroll
    for (int off = 32; off; off >>= 1) m = fmaxf(m, __shfl_xor(m, off));
    __shared__ float sm[4];
    int wid = threadIdx.x >> 6;
    if ((threadIdx.x & 63) == 0) sm[wid] = m;
    __syncthreads();
    if (threadIdx.x == 0)
        atomicMax(gm, fenc(fmaxf(fmaxf(sm[0], sm[1]), fmaxf(sm[2], sm[3]))));
}

// wave per dst node, single edge pass, prep-then-broadcast (2-deep, R12),
// packed fp16 accumulation (R14).
__global__ __launch_bounds__(256) void k_agg1(const int* __restrict__ row, const int* __restrict__ csr,
                                              const float* __restrict__ als, const float* __restrict__ ald,
                                              const __half* __restrict__ h, const float* __restrict__ b,
                                              const unsigned* __restrict__ gmaxu, __half* __restrict__ out,
                                              int n) {
    int node = blockIdx.x * 4 + (threadIdx.x >> 6);
    if (node >= n) return;
    int lane = threadIdx.x & 63;
    int start = __builtin_amdgcn_readfirstlane(row[node]);
    int end   = __builtin_amdgcn_readfirstlane(row[node + 1]);

    int g = lane >> 4;
    int lig = lane & 15;
    int head = lig >> 2;

    float4 adv = *(const float4*)(ald + (size_t)node * 4);
    uint4 gu = *(const uint4*)gmaxu;
    float mt, mh0, mh1, mh2, mh3;
    mt = fdec(gu.x) + adv.x; mh0 = mt > 0.f ? mt : SLOPE * mt;
    mt = fdec(gu.y) + adv.y; mh1 = mt > 0.f ? mt : SLOPE * mt;
    mt = fdec(gu.z) + adv.z; mh2 = mt > 0.f ? mt : SLOPE * mt;
    mt = fdec(gu.w) + adv.w; mh3 = mt > 0.f ? mt : SLOPE * mt;

    const __half2 z2 = __floats2half2_rn(0.f, 0.f);
    float den0 = 0.f, den1 = 0.f, den2 = 0.f, den3 = 0.f;
    __half2 ah0 = z2, ah1 = z2, ah2 = z2, ah3 = z2;

    for (int k0 = start; k0 < end; k0 += 64) {
        int nb = end - k0; if (nb > 64) nb = 64;
        int s_l = (lane < nb) ? csr[k0 + lane] : 0;
        float4 av = *(const float4*)(als + (size_t)s_l * 4);
        float e, x0, x1, x2, x3;
        e = av.x + adv.x; e = e > 0.f ? e : SLOPE * e; x0 = __expf(e - mh0);
        e = av.y + adv.y; e = e > 0.f ? e : SLOPE * e; x1 = __expf(e - mh1);
        e = av.z + adv.z; e = e > 0.f ? e : SLOPE * e; x2 = __expf(e - mh2);
        e = av.w + adv.w; e = e > 0.f ? e : SLOPE * e; x3 = __expf(e - mh3);
        bool valid = lane < nb;
        x0 = valid ? x0 : 0.f; x1 = valid ? x1 : 0.f;
        x2 = valid ? x2 : 0.f; x3 = valid ? x3 : 0.f;
        den0 += x0; den1 += x1; den2 += x2; den3 += x3;
        __half2 p01 = __floats2half2_rn(x0, x1);
        __half2 p23 = __floats2half2_rn(x2, x3);
        int w01 = h22i(p01);
        int w23 = h22i(p23);

        for (int jj = 0; jj < nb; jj += 8) {
            int eA = jj + g;
            int eB = jj + 4 + g;
            int sA = __shfl(s_l, eA);
            int sB = __shfl(s_l, eB);
            int wA01 = __shfl(w01, eA);
            int wA23 = __shfl(w23, eA);
            int wB01 = __shfl(w01, eB);
            int wB23 = __shfl(w23, eB);
            int wA = (head & 2) ? wA23 : wA01;
            int wB = (head & 2) ? wB23 : wB01;
            uint4 hvA = *(const uint4*)(h + ((size_t)sA << 7) + lig * 8);
            uint4 hvB = *(const uint4*)(h + ((size_t)sB << 7) + lig * 8);
            __half exhA = (head & 1) ? __high2half(i2h2(wA)) : __low2half(i2h2(wA));
            __half exhB = (head & 1) ? __high2half(i2h2(wB)) : __low2half(i2h2(wB));
            __half2 exA2 = __half2half2(exhA);
            __half2 exB2 = __half2half2(exhB);
            exA2 = (eA < nb) ? exA2 : z2;
            exB2 = (eB < nb) ? exB2 : z2;
            ah0 = __hfma2(exA2, i2h2((int)hvA.x), ah0);
            ah1 = __hfma2(exA2, i2h2((int)hvA.y), ah1);
            ah2 = __hfma2(exA2, i2h2((int)hvA.z), ah2);
            ah3 = __hfma2(exA2, i2h2((int)hvA.w), ah3);
            ah0 = __hfma2(exB2, i2h2((int)hvB.x), ah0);
            ah1 = __hfma2(exB2, i2h2((int)hvB.y), ah1);
            ah2 = __hfma2(exB2, i2h2((int)hvB.z), ah2);
            ah3 = __hfma2(exB2, i2h2((int)hvB.w), ah3);
        }
    }
#pragma unroll
    for (int off = 32; off; off >>= 1) {
        den0 += __shfl_xor(den0, off);
        den1 += __shfl_xor(den1, off);
        den2 += __shfl_xor(den2, off);
        den3 += __shfl_xor(den3, off);
    }
    ah0 = __hadd2(ah0, h2shflxor(ah0, 16));
    ah1 = __hadd2(ah1, h2shflxor(ah1, 16));
    ah2 = __hadd2(ah2, h2shflxor(ah2, 16));
    ah3 = __hadd2(ah3, h2shflxor(ah3, 16));
    ah0 = __hadd2(ah0, h2shflxor(ah0, 32));
    ah1 = __hadd2(ah1, h2shflxor(ah1, 32));
    ah2 = __hadd2(ah2, h2shflxor(ah2, 32));
    ah3 = __hadd2(ah3, h2shflxor(ah3, 32));
    if (g == 0) {
        float den_h = (head & 2) ? ((head & 1) ? den3 : den2) : ((head & 1) ? den1 : den0);
        float inv = 1.f / den_h;
        float2 f0 = __half22float2(ah0);
        float2 f1 = __half22float2(ah1);
        float2 f2 = __half22float2(ah2);
        float2 f3 = __half22float2(ah3);
        float4 bv0 = *(const float4*)(b + lig * 8);
        float4 bv1 = *(const float4*)(b + lig * 8 + 4);
        float o0, o1, o2, o3, o4, o5, o6, o7;
        o0 = f0.x * inv + bv0.x; o0 = o0 > 0.f ? o0 : expm1f(o0);
        o1 = f0.y * inv + bv0.y; o1 = o1 > 0.f ? o1 : expm1f(o1);
        o2 = f1.x * inv + bv0.z; o2 = o2 > 0.f ? o2 : expm1f(o2);
        o3 = f1.y * inv + bv0.w; o3 = o3 > 0.f ? o3 : expm1f(o3);
        o4 = f2.x * inv + bv1.x; o4 = o4 > 0.f ? o4 : expm1f(o4);
        o5 = f2.y * inv + bv1.y; o5 = o5 > 0.f ? o5 : expm1f(o5);
        o6 = f3.x * inv + bv1.z; o6 = o6 > 0.f ? o6 : expm1f(o6);
        o7 = f3.y * inv + bv1.w; o7 = o7 > 0.f ? o7 : expm1f(o7);
        __half2 q0 = __floats2half2_rn(o0, o1);
        __half2 q1 = __floats2half2_rn(o2, o3);
        __half2 q2 = __floats2half2_rn(o4, o5);
        __half2 q3 = __floats2half2_rn(o6, o7);
        uint4 st;
        st.x = (unsigned)h22i(q0);
        st.y = (unsigned)h22i(q1);
        st.z = (unsigned)h22i(q2);
        st.w = (unsigned)h22i(q3);
        *(uint4*)(out + ((size_t)node << 7) + lig * 8) = st;
    }
}

// ------- Layer 2 GEMM: h2 = hm(fp16) @ W2 (128->40), fp16 out -------

__global__ __launch_bounds__(640) void k_gemm2(const __half* __restrict__ hm, const float* __restrict__ W2,
                                               __half* __restrict__ h2h, int n) {
    __shared__ float xs[16][128];
    __shared__ float ws[128 * 40];
    int t = threadIdx.x;
    int row0 = blockIdx.x * 16;
    for (int i = t; i < 128 * 40; i += 640) ws[i] = W2[i];
    if (t < 256) {
        int r = t >> 4, c8 = t & 15;
        int gr = row0 + r;
        float* d = &xs[r][c8 * 8];
        if (gr < n) {
            uint4 v = *(const uint4*)(hm + (size_t)gr * 128 + c8 * 8);
            float2 f0 = __half22float2(*reinterpret_cast<__half2*>(&v.x));
            float2 f1 = __half22float2(*reinterpret_cast<__half2*>(&v.y));
            float2 f2 = __half22float2(*reinterpret_cast<__half2*>(&v.z));
            float2 f3 = __half22float2(*reinterpret_cast<__half2*>(&v.w));
            d[0] = f0.x; d[1] = f0.y; d[2] = f1.x; d[3] = f1.y;
            d[4] = f2.x; d[5] = f2.y; d[6] = f3.x; d[7] = f3.y;
        } else {
            for (int j = 0; j < 8; j++) d[j] = 0.f;
        }
    }
    __syncthreads();
    int r = t / 40, c = t - r * 40;
    int gr = row0 + r;
    float acc = 0.f;
#pragma unroll 8
    for (int k = 0; k < 128; ++k) acc += xs[r][k] * ws[k * 40 + c];
    if (gr < n) h2h[(size_t)gr * 40 + c] = __float2half_rn(acc);
}

// wave per node; lanes 0-19 load 2 ch each (no atomics).
__global__ __launch_bounds__(256) void k_al2(const __half* __restrict__ h2, const float* __restrict__ a_s,
                                             const float* __restrict__ a_d, float* als, float* ald, int n) {
    int t = threadIdx.x;
    int node = blockIdx.x * 4 + (t >> 6);
    int l = t & 63;
    if (node >= n) return;
    float ps = 0.f, pd = 0.f;
    if (l < 20) {
        unsigned hv = *(const unsigned*)(h2 + (size_t)node * 40 + l * 2);
        float2 f = __half22float2(*reinterpret_cast<__half2*>(&hv));
        float2 vs = *(const float2*)(a_s + l * 2);
        float2 vd = *(const float2*)(a_d + l * 2);
        ps = f.x * vs.x + f.y * vs.y;
        pd = f.x * vd.x + f.y * vd.y;
    }
#pragma unroll
    for (int off = 32; off; off >>= 1) { ps += __shfl_xor(ps, off); pd += __shfl_xor(pd, off); }
    if (l == 0) { als[node] = ps; ald[node] = pd; }
}

// wave per node, single edge pass + log_softmax (2-deep, packed fp16 acc).
__global__ __launch_bounds__(256) void k_agg2(const int* __restrict__ row, const int* __restrict__ csr,
                                              const float* __restrict__ als, const float* __restrict__ ald,
                                              const __half* __restrict__ h2, const float* __restrict__ b2,
                                              const unsigned* __restrict__ gmaxu, float* __restrict__ out,
                                              int n) {
    int node = blockIdx.x * 4 + (threadIdx.x >> 6);
    if (node >= n) return;
    int lane = threadIdx.x & 63;
    int start = __builtin_amdgcn_readfirstlane(row[node]);
    int end   = __builtin_amdgcn_readfirstlane(row[node + 1]);
    float ad = ald[node];
    float mt = fdec(gmaxu[0]) + ad;
    float mh = mt > 0.f ? mt : SLOPE * mt;

    int g = lane / 5;
    int lig = lane - g * 5;
    bool act = g < 12;

    const __half2 z2 = __floats2half2_rn(0.f, 0.f);
    float den = 0.f;
    __half2 ah0 = z2, ah1 = z2, ah2 = z2, ah3 = z2;
    for (int k0 = start; k0 < end; k0 += 64) {
        int nb = end - k0; if (nb > 64) nb = 64;
        int s_l = (lane < nb) ? csr[k0 + lane] : 0;
        float e = als[s_l] + ad; e = e > 0.f ? e : SLOPE * e;
        float ex_l = __expf(e - mh);
        ex_l = (lane < nb) ? ex_l : 0.f;
        den += ex_l;
        __half exh_l = __float2half_rn(ex_l);
        int exi_l = h22i(__half2half2(exh_l));

        for (int jj = 0; jj < nb; jj += 24) {
            int eA = jj + g;
            int eB = jj + 12 + g;
            int sA = __shfl(s_l, eA & 63);
            int sB = __shfl(s_l, eB & 63);
            int exAi = __shfl(exi_l, eA & 63);
            int exBi = __shfl(exi_l, eB & 63);
            uint4 hvA = *(const uint4*)(h2 + (size_t)sA * 40 + lig * 8);
            uint4 hvB = *(const uint4*)(h2 + (size_t)sB * 40 + lig * 8);
            __half2 exA2 = i2h2(exAi);
            __half2 exB2 = i2h2(exBi);
            exA2 = (act && eA < nb) ? exA2 : z2;
            exB2 = (act && eB < nb) ? exB2 : z2;
            ah0 = __hfma2(exA2, i2h2((int)hvA.x), ah0);
            ah1 = __hfma2(exA2, i2h2((int)hvA.y), ah1);
            ah2 = __hfma2(exA2, i2h2((int)hvA.z), ah2);
            ah3 = __hfma2(exA2, i2h2((int)hvA.w), ah3);
            ah0 = __hfma2(exB2, i2h2((int)hvB.x), ah0);
            ah1 = __hfma2(exB2, i2h2((int)hvB.y), ah1);
            ah2 = __hfma2(exB2, i2h2((int)hvB.z), ah2);
            ah3 = __hfma2(exB2, i2h2((int)hvB.w), ah3);
        }
    }
#pragma unroll
    for (int off = 32; off; off >>= 1) den += __shfl_xor(den, off);
    int t1i;
    t1i = __shfl(h22i(ah0), (lane + 30) & 63); ah0 = __hadd2(ah0, i2h2(t1i));
    t1i = __shfl(h22i(ah1), (lane + 30) & 63); ah1 = __hadd2(ah1, i2h2(t1i));
    t1i = __shfl(h22i(ah2), (lane + 30) & 63); ah2 = __hadd2(ah2, i2h2(t1i));
    t1i = __shfl(h22i(ah3), (lane + 30) & 63); ah3 = __hadd2(ah3, i2h2(t1i));
    t1i = __shfl(h22i(ah0), (lane + 15) & 63); ah0 = __hadd2(ah0, i2h2(t1i));
    t1i = __shfl(h22i(ah1), (lane + 15) & 63); ah1 = __hadd2(ah1, i2h2(t1i));
    t1i = __shfl(h22i(ah2), (lane + 15) & 63); ah2 = __hadd2(ah2, i2h2(t1i));
    t1i = __shfl(h22i(ah3), (lane + 15) & 63); ah3 = __hadd2(ah3, i2h2(t1i));
    int t2i;
    t1i = __shfl(h22i(ah0), (lane + 5) & 63); t2i = __shfl(h22i(ah0), (lane + 10) & 63);
    ah0 = __hadd2(__hadd2(ah0, i2h2(t1i)), i2h2(t2i));
    t1i = __shfl(h22i(ah1), (lane + 5) & 63); t2i = __shfl(h22i(ah1), (lane + 10) & 63);
    ah1 = __hadd2(__hadd2(ah1, i2h2(t1i)), i2h2(t2i));
    t1i = __shfl(h22i(ah2), (lane + 5) & 63); t2i = __shfl(h22i(ah2), (lane + 10) & 63);
    ah2 = __hadd2(__hadd2(ah2, i2h2(t1i)), i2h2(t2i));
    t1i = __shfl(h22i(ah3), (lane + 5) & 63); t2i = __shfl(h22i(ah3), (lane + 10) & 63);
    ah3 = __hadd2(__hadd2(ah3, i2h2(t1i)), i2h2(t2i));

    float v0 = 0.f, v1 = 0.f, v2 = 0.f, v3 = 0.f, v4 = 0.f, v5 = 0.f, v6 = 0.f, v7 = 0.f;
    float mv = -INFINITY;
    if (lane < 5) {
        float inv = 1.f / den;
        float2 f0 = __half22float2(ah0);
        float2 f1 = __half22float2(ah1);
        float2 f2 = __half22float2(ah2);
        float2 f3 = __half22float2(ah3);
        float4 bv0 = *(const float4*)(b2 + lane * 8);
        float4 bv1 = *(const float4*)(b2 + lane * 8 + 4);
        v0 = f0.x * inv + bv0.x; v1 = f0.y * inv + bv0.y;
        v2 = f1.x * inv + bv0.z; v3 = f1.y * inv + bv0.w;
        v4 = f2.x * inv + bv1.x; v5 = f2.y * inv + bv1.y;
        v6 = f3.x * inv + bv1.z; v7 = f3.y * inv + bv1.w;
        mv = fmaxf(fmaxf(fmaxf(v0, v1), fmaxf(v2, v3)),
                   fmaxf(fmaxf(v4, v5), fmaxf(v6, v7)));
    }
#pragma unroll
    for (int off = 32; off; off >>= 1) mv = fmaxf(mv, __shfl_xor(mv, off));
    float se = 0.f;
    if (lane < 5)
        se = __expf(v0 - mv) + __expf(v1 - mv) + __expf(v2 - mv) + __expf(v3 - mv)
           + __expf(v4 - mv) + __expf(v5 - mv) + __expf(v6 - mv) + __expf(v7 - mv);
#pragma unroll
    for (int off = 32; off; off >>= 1) se += __shfl_xor(se, off);
    if (lane < 5) {
        float lse = mv + __logf(se);
        float4 o0, o1;
        o0.x = v0 - lse; o0.y = v1 - lse; o0.z = v2 - lse; o0.w = v3 - lse;
        o1.x = v4 - lse; o1.y = v5 - lse; o1.z = v6 - lse; o1.w = v7 - lse;
        *(float4*)(out + (size_t)node * 40 + lane * 8) = o0;
        *(float4*)(out + (size_t)node * 40 + lane * 8 + 4) = o1;
    }
}

// ---------------- launch ----------------

extern "C" void kernel_launch(void* const* d_in, const int* in_sizes, int n_in,
                              void* d_out, int out_size, void* d_ws, size_t ws_size,
                              hipStream_t stream) {
    const float* x   = (const float*)d_in[0];
    const int*   ei  = (const int*)d_in[1];
    const float* W1  = (const float*)d_in[2];
    const float* as1 = (const float*)d_in[3];
    const float* ad1 = (const float*)d_in[4];
    const float* b1  = (const float*)d_in[5];
    const float* W2  = (const float*)d_in[6];
    const float* as2 = (const float*)d_in[7];
    const float* ad2 = (const float*)d_in[8];
    const float* b2  = (const float*)d_in[9];
    float* out = (float*)d_out;

    int n = in_sizes[0] / 128;
    int E = in_sizes[1] / 2;
    const int* src = ei;
    const int* dst = ei + E;
    int etot = E + n;

    int nbuck = (n + NB - 1) / NB;
    int cap = (2 * (E / nbuck) + 1023) / 1024 * 1024;

    char* ws = (char*)d_ws;
    size_t off = 0;
    auto alloc = [&](size_t bytes) {
        void* p = ws + off;
        off += (bytes + 255) & ~(size_t)255;
        return p;
    };
    int*      rowp   = (int*)alloc((size_t)(n + 1) * 4);
    int*      csr    = (int*)alloc((size_t)etot * 4);
    __half*   h1h    = (__half*)alloc((size_t)n * 128 * 2);
    __half*   hmh    = (__half*)alloc((size_t)n * 128 * 2);
    float*    als1   = (float*)alloc((size_t)n * 4 * 4);
    float*    ald1   = (float*)alloc((size_t)n * 4 * 4);
    unsigned* gmaxu  = (unsigned*)alloc(256);
    unsigned* gcnt   = (unsigned*)alloc((size_t)nbuck * 4);
    unsigned* gbase  = (unsigned*)alloc((size_t)nbuck * 4);
    unsigned* binbuf = (unsigned*)alloc((size_t)nbuck * cap * 4);  // own region: bin runs
                                                                   // CONCURRENT with gemm1 (R17)
    // layer-2 features overlay h1h (h1h dead after agg1)
    __half* h2h = h1h;
    float* als2 = als1;
    float* ald2 = ald1;

    int epb = (E + 1023) / 1024;
    int binBlocks = 1024;
    int gemm1Blocks = (n + 31) / 32;

    hipMemsetAsync(gcnt, 0, (size_t)nbuck * 4, stream);
    hipMemsetAsync(gmaxu, 0, 32, stream);

    k_binGemm1<<<binBlocks + gemm1Blocks, 256, 0, stream>>>(
        src, dst, gcnt, binbuf, E, nbuck, cap, epb, binBlocks,
        x, W1, as1, ad1, h1h, als1, ald1, n);
    k_bscanGmax4<<<257, 256, 0, stream>>>(gcnt, gbase, rowp, n, nbuck, etot,
                                          (const float4*)als1, gmaxu);
    k_build<<<nbuck, 256, 0, stream>>>(gcnt, gbase, binbuf, rowp, csr, n, cap);
    k_agg1<<<(n + 3) / 4, 256, 0, stream>>>(rowp, csr, als1, ald1, h1h, b1, gmaxu, hmh, n);

    k_gemm2<<<(n + 15) / 16, 640, 0, stream>>>(hmh, W2, h2h, n);
    k_al2<<<(n + 3) / 4, 256, 0, stream>>>(h2h, as2, ad2, als2, ald2, n);
    k_gmax1<<<256, 256, 0, stream>>>(als2, gmaxu + 4, n);
    k_agg2<<<(n + 3) / 4, 256, 0, stream>>>(rowp, csr, als2, ald2, h2h, b2, gmaxu + 4, out, n);
}